// Round 10
// baseline (425.735 us; speedup 1.0000x reference)
//
#include <hip/hip_runtime.h>

typedef unsigned short u16;
typedef __attribute__((ext_vector_type(8))) short bf16x8;
typedef __attribute__((ext_vector_type(4))) float f32x4;
#define EPSV 1e-5f
#define LOG2E 1.4426950408889634f

__device__ __forceinline__ float b2f(u16 u) {
  union { float f; unsigned int i; } v; v.i = ((unsigned int)u) << 16; return v.f;
}
__device__ __forceinline__ u16 f2b(float f) {
  union { float f; unsigned int i; } v; v.f = f;
  unsigned int r = v.i + 0x7FFFu + ((v.i >> 16) & 1u);
  return (u16)(r >> 16);
}
__device__ __forceinline__ u16 f2b_trunc(float f) {
  union { float f; unsigned int i; } v; v.f = f;
  return (u16)(v.i >> 16);
}
__device__ __forceinline__ float silu_(float z) { return z / (1.f + exp2f(-LOG2E * z)); }

// ---------------- dtype detect ----------------
__global__ __launch_bounds__(128) void detect_k(const u16* __restrict__ xp, float* __restrict__ flag) {
  __shared__ int cnt[2];
  int t = threadIdx.x;
  if (t < 2) cnt[t] = 0;
  __syncthreads();
  u16 u = xp[t * 2];
  int e = (u >> 7) & 0xff;
  if (e != 0 && (e < 90 || e > 160)) atomicAdd(&cnt[0], 1);
  if (u == 0) atomicAdd(&cnt[1], 1);
  __syncthreads();
  if (t == 0) *flag = (cnt[0] > 16 || cnt[1] > 64) ? 1.f : 0.f;
}

// ---------------- input conversion ----------------

struct ConvArgs {
  const void* src[30];
  long dst[30];
  int end[30];
  int mode[30];
};

__global__ __launch_bounds__(256) void convert_all(ConvArgs a, float* __restrict__ wsF,
                                                   u16* __restrict__ wsH,
                                                   const float* __restrict__ flagp, int total) {
  const int flag = (*flagp > 0.5f);
  int gid = blockIdx.x * 256 + threadIdx.x;
  if (gid >= total) return;
  #pragma unroll 1
  for (int s = 0; s < 30; ++s) {
    if (gid < a.end[s]) {
      int idx = gid - (s ? a.end[s - 1] : 0);
      if (a.mode[s] == 0) {
        float v = flag ? ((const float*)a.src[s])[idx] : b2f(((const u16*)a.src[s])[idx]);
        wsF[a.dst[s] + idx] = v;
      } else {
        u16 h = flag ? f2b(((const float*)a.src[s])[idx]) : ((const u16*)a.src[s])[idx];
        wsH[a.dst[s] + idx] = h;
      }
      return;
    }
  }
}

// conv3 weight transform: fp32 W[o][I][3][3] -> bf16 Wt[I/32][tap][256o][32ch]
__global__ __launch_bounds__(256) void w3t(const float* __restrict__ Wsrc, u16* __restrict__ Wdst) {
  int idx = blockIdx.x * 256 + threadIdx.x;
  int ch = idx & 31;
  int o  = (idx >> 5) & 255;
  int tap = (idx >> 13) % 9;
  int c8 = (idx >> 13) / 9;
  int i = c8 * 32 + ch;
  Wdst[idx] = f2b(Wsrc[((long)o * 256 + i) * 9 + tap]);
}

// ---------------- CoordAtt ----------------

__global__ __launch_bounds__(256) void plane_means(const float* __restrict__ x, float* __restrict__ yin) {
  __shared__ float pl[4096];
  int bc = blockIdx.x, t = threadIdx.x;
  const float* xp = x + (long)bc * 4096;
  for (int j = 0; j < 16; ++j) { int id = j * 256 + t; pl[id] = xp[id]; }
  __syncthreads();
  if (t < 64) {
    float s = 0.f;
    for (int w = 0; w < 64; ++w) s += pl[t * 64 + w];
    yin[(long)bc * 128 + t] = s * (1.f / 64.f);
  } else if (t < 128) {
    int w = t - 64; float s = 0.f;
    for (int h = 0; h < 64; ++h) s += pl[h * 64 + w];
    yin[(long)bc * 128 + 64 + w] = s * (1.f / 64.f);
  }
}

// grid (2 b x 8 o)
__global__ __launch_bounds__(128) void ca_conv1(const float* __restrict__ yin, const float* __restrict__ w1,
                                                const float* __restrict__ b1, const float* __restrict__ bnp,
                                                float* __restrict__ ybn) {
  int b = blockIdx.x, o = blockIdx.y, p = threadIdx.x;
  float acc = 0.f;
  for (int c = 0; c < 256; ++c)
    acc += w1[o * 256 + c] * yin[((long)b * 256 + c) * 128 + p];
  float z = acc + b1[o];
  float g = bnp[o], bt = bnp[8 + o], mn = bnp[16 + o], vr = bnp[24 + o];
  float s = g * rsqrtf(vr + EPSV);
  z = z * s + (bt - mn * s);
  float hs = fminf(fmaxf(z + 3.f, 0.f), 6.f) * (1.f / 6.f);
  ybn[((long)b * 8 + o) * 128 + p] = z * hs;
}

// ca_gate fused: recompute the two sigmoids per element (ybn is 2KB, L1-hot)
__global__ __launch_bounds__(256) void apply_ca(const float* __restrict__ x, const float* __restrict__ ybn,
    const float* __restrict__ wh, const float* __restrict__ bh,
    const float* __restrict__ ww, const float* __restrict__ bw,
    u16* __restrict__ r) {
  int idx = blockIdx.x * 256 + threadIdx.x;
  int n = idx & 4095, bc = idx >> 12;
  int b = bc >> 8, c = bc & 255;
  int h = n >> 6, w = n & 63;
  const float* yb = ybn + (long)b * 1024;   // [8][128]
  float d1 = bh[c], d2 = bw[c];
  #pragma unroll
  for (int o = 0; o < 8; ++o) {
    d1 += wh[c * 8 + o] * yb[o * 128 + h];
    d2 += ww[c * 8 + o] * yb[o * 128 + 64 + w];
  }
  float ah = 1.f / (1.f + exp2f(-LOG2E * d1));
  float aw = 1.f / (1.f + exp2f(-LOG2E * d2));
  r[idx] = f2b(x[idx] * ah * aw);
}

// ---------------- MFMA 1x1 conv, 64o x 64n tile: bf16 in ----------------
// v10: BK=64 -- 8 MFMAs + 4 ds_read_b128 per barrier (was 4+2); K-loop barriers halved
//      (K=256 -> 4). Double-buffered Bs[2][64n][72k]; A direct-from-global named regs.
//      MFMA accumulation order identical to two BK=32 steps -> bit-identical results.
// OUTH: 0 = fp32 linear, 1 = bf16 linear [ch][n], 2 = bf16 V-swizzled [n/32][ch][n%32],
//       3 = bf16 TRANSPOSED [n][64] (fuses transpose_hh), 4 = fp32 + bf16 dual (fuses cvtb)

template<int ACT, int OUTH>
__global__ __launch_bounds__(256) void mfma_cbs(
    const u16* __restrict__ Wbf, long aBS,
    const u16* __restrict__ In, long bBS,
    void* __restrict__ Out, long oBS,
    int O, int K, int N,
    const float* __restrict__ bnp, const float* __restrict__ bias,
    void* __restrict__ Out2)
{
  __shared__ u16 Bs[2][64 * 72];
  __shared__ float albe[64][2];
  const int t = threadIdx.x;
  const int n0 = blockIdx.x * 64;
  const int o0 = blockIdx.y * 64;
  const int b  = blockIdx.z;
  const int w = t >> 6, l = t & 63, lq = l >> 4, lr = l & 15;
  const int wo = (w >> 1) * 32, wn = (w & 1) * 32;
  if (t < 64) {
    int o = o0 + t;
    float al = 1.f, be = 0.f;
    if (bnp) {
      float g = bnp[o], bt = bnp[O + o], mn = bnp[2 * O + o], vr = bnp[3 * O + o];
      al = g * rsqrtf(vr + EPSV); be = bt - mn * al;
    }
    if (bias) be += bias[o];
    albe[t][0] = al; albe[t][1] = be;
  }
  const u16* Ab = Wbf + (long)b * aBS;
  const u16* inb = In + (long)b * bBS + n0;
  const u16* a0p = Ab + (long)(o0 + wo + lr) * K + lq * 8;
  const u16* a1p = a0p + (long)16 * K;
  const int bk = t >> 3, bn8 = (t & 7) * 8;   // bk in [0,32): k rows bk and bk+32
  f32x4 acc[2][2] = {};
  // ---- prologue: stage Bs[0] (kc=0, 64 k-rows); prefetch B(kc=64) + A(kc=0) ----
  uint4 b0 = *(const uint4*)(inb + (long)bk * N + bn8);
  uint4 b1 = *(const uint4*)(inb + (long)(32 + bk) * N + bn8);
  {
    union { uint4 q; u16 h[8]; } t0, t1; t0.q = b0; t1.q = b1;
    #pragma unroll
    for (int j = 0; j < 8; ++j) {
      Bs[0][(bn8 + j) * 72 + bk]      = t0.h[j];
      Bs[0][(bn8 + j) * 72 + 32 + bk] = t1.h[j];
    }
  }
  b0 = *(const uint4*)(inb + (long)(64 + bk) * N + bn8);        // K >= 256 always
  b1 = *(const uint4*)(inb + (long)(96 + bk) * N + bn8);
  uint4 a00 = *(const uint4*)(a0p);
  uint4 a01 = *(const uint4*)(a0p + 32);
  uint4 a10 = *(const uint4*)(a1p);
  uint4 a11 = *(const uint4*)(a1p + 32);
  __syncthreads();
  for (int kc = 0; kc < K; kc += 64) {
    const int p = (kc >> 6) & 1;
    // stage NEXT 64-k tile into the other buffer (b0/b1 hold B(kc+64))
    {
      union { uint4 q; u16 h[8]; } t0, t1; t0.q = b0; t1.q = b1;
      #pragma unroll
      for (int j = 0; j < 8; ++j) {
        Bs[p ^ 1][(bn8 + j) * 72 + bk]      = t0.h[j];
        Bs[p ^ 1][(bn8 + j) * 72 + 32 + bk] = t1.h[j];
      }
    }
    int kn = kc + 64;  if (kn >= K) kn = 0;     // A for next iter (wrapped dummy)
    int kb = kc + 128; if (kb >= K) kb = 0;     // B for iter after next (wrapped dummy)
    uint4 a00n = *(const uint4*)(a0p + kn);
    uint4 a01n = *(const uint4*)(a0p + kn + 32);
    uint4 a10n = *(const uint4*)(a1p + kn);
    uint4 a11n = *(const uint4*)(a1p + kn + 32);
    uint4 b0n = *(const uint4*)(inb + (long)(kb + bk) * N + bn8);
    uint4 b1n = *(const uint4*)(inb + (long)(kb + 32 + bk) * N + bn8);
    // k-half 0
    bf16x8 bfv0 = *(const bf16x8*)&Bs[p][(wn + lr) * 72 + lq * 8];
    bf16x8 bfv1 = *(const bf16x8*)&Bs[p][(wn + 16 + lr) * 72 + lq * 8];
    acc[0][0] = __builtin_amdgcn_mfma_f32_16x16x32_bf16(*(const bf16x8*)&a00, bfv0, acc[0][0], 0, 0, 0);
    acc[0][1] = __builtin_amdgcn_mfma_f32_16x16x32_bf16(*(const bf16x8*)&a00, bfv1, acc[0][1], 0, 0, 0);
    acc[1][0] = __builtin_amdgcn_mfma_f32_16x16x32_bf16(*(const bf16x8*)&a10, bfv0, acc[1][0], 0, 0, 0);
    acc[1][1] = __builtin_amdgcn_mfma_f32_16x16x32_bf16(*(const bf16x8*)&a10, bfv1, acc[1][1], 0, 0, 0);
    // k-half 1
    bfv0 = *(const bf16x8*)&Bs[p][(wn + lr) * 72 + 32 + lq * 8];
    bfv1 = *(const bf16x8*)&Bs[p][(wn + 16 + lr) * 72 + 32 + lq * 8];
    acc[0][0] = __builtin_amdgcn_mfma_f32_16x16x32_bf16(*(const bf16x8*)&a01, bfv0, acc[0][0], 0, 0, 0);
    acc[0][1] = __builtin_amdgcn_mfma_f32_16x16x32_bf16(*(const bf16x8*)&a01, bfv1, acc[0][1], 0, 0, 0);
    acc[1][0] = __builtin_amdgcn_mfma_f32_16x16x32_bf16(*(const bf16x8*)&a11, bfv0, acc[1][0], 0, 0, 0);
    acc[1][1] = __builtin_amdgcn_mfma_f32_16x16x32_bf16(*(const bf16x8*)&a11, bfv1, acc[1][1], 0, 0, 0);
    a00 = a00n; a01 = a01n; a10 = a10n; a11 = a11n; b0 = b0n; b1 = b1n;
    __syncthreads();   // Bs[p^1] visible for next iter
  }
  float* ob = (float*)Out + (long)b * oBS;
  u16* obh = (u16*)Out + (long)b * oBS;
  u16* obh2 = Out2 ? (u16*)Out2 + (long)b * oBS : nullptr;
  if (OUTH == 3) {
    // transposed [n][O] write: pack 4 consecutive o (r=0..3) into one 8B store
    #pragma unroll
    for (int i = 0; i < 2; ++i) {
      #pragma unroll
      for (int j = 0; j < 2; ++j) {
        int n = n0 + wn + j * 16 + lr;
        union { u16 h[4]; uint2 q; } pk;
        #pragma unroll
        for (int r = 0; r < 4; ++r) {
          int ol = wo + i * 16 + lq * 4 + r;
          float vv = acc[i][j][r] * albe[ol][0] + albe[ol][1];
          if (ACT) vv = silu_(vv);
          pk.h[r] = f2b(vv);
        }
        *(uint2*)&obh[(long)n * 64 + o0 + wo + i * 16 + lq * 4] = pk.q;
      }
    }
  } else {
    #pragma unroll
    for (int i = 0; i < 2; ++i) {
      #pragma unroll
      for (int r = 0; r < 4; ++r) {
        int ol = wo + i * 16 + lq * 4 + r;
        float al = albe[ol][0], be = albe[ol][1];
        #pragma unroll
        for (int j = 0; j < 2; ++j) {
          float vv = acc[i][j][r] * al + be;
          if (ACT) vv = silu_(vv);
          if (OUTH == 2) {
            int col = n0 + wn + j * 16 + lr;
            obh[((long)(col >> 5) * 256 + (o0 + ol)) * 32 + (col & 31)] = f2b(vv);
          } else if (OUTH == 1) {
            obh[(long)(o0 + ol) * N + n0 + wn + j * 16 + lr] = f2b(vv);
          } else {  // 0 or 4: fp32 linear
            ob[(long)(o0 + ol) * N + n0 + wn + j * 16 + lr] = vv;
            if (OUTH == 4)
              obh2[(long)(o0 + ol) * N + n0 + wn + j * 16 + lr] = f2b(vv);
          }
        }
      }
    }
  }
}

// ---------------- MFMA 3x3 conv (implicit GEMM), bf16 in/out ----------------
// one output ROW per block (512 blocks = 2/CU); 3-row double-buffered stage ->
// ONE barrier per c8 step; weights direct-from-global; wave = 64o x 16px.
__global__ __launch_bounds__(256) void conv3_mfma(
    const u16* __restrict__ Wt,
    const u16* __restrict__ In, long iBS,
    u16* __restrict__ Out, long oBS, int O, int I,
    const float* __restrict__ bnp)
{
  __shared__ u16 Bs[2][3 * 66 * 34];
  __shared__ float albe[64][2];
  const int t = threadIdx.x;
  const int h0 = blockIdx.x;
  const int o0 = blockIdx.y * 64;
  const int b  = blockIdx.z;
  const int w = t >> 6, l = t & 63, lq = l >> 4, lr = l & 15;
  const int wn = w * 16;
  if (t < 64) {
    int o = o0 + t;
    float g = bnp[o], bt = bnp[O + o], mn = bnp[2 * O + o], vr = bnp[3 * O + o];
    float al = g * rsqrtf(vr + EPSV);
    albe[t][0] = al; albe[t][1] = bt - mn * al;
  }
  if (t < 192) {
    int r = t >> 6, cs = (t >> 5) & 1, ch = t & 31;
    Bs[0][(r * 66 + (cs ? 65 : 0)) * 34 + ch] = 0;
    Bs[1][(r * 66 + (cs ? 65 : 0)) * 34 + ch] = 0;
  }
  const u16* inb = In + (long)b * iBS;
  const int bch = t >> 3, bcg = (t & 7) * 8;
  const u16* wlane = Wt + (long)(o0 + lr) * 32 + lq * 8;
  const int nC8 = I >> 5;
  f32x4 acc[4] = {};

  uint4 tb0, tb1, tb2;
  {
    const u16* cb = inb + (long)bch * 4096 + bcg;
    tb0 = (h0 - 1 >= 0) ? *(const uint4*)(cb + (h0 - 1) * 64) : make_uint4(0,0,0,0);
    tb1 = *(const uint4*)(cb + h0 * 64);
    tb2 = (h0 + 1 < 64) ? *(const uint4*)(cb + (h0 + 1) * 64) : make_uint4(0,0,0,0);
  }
  {
    union { uint4 q; u16 h[8]; } u0, u1, u2;
    u0.q = tb0; u1.q = tb1; u2.q = tb2;
    #pragma unroll
    for (int j2 = 0; j2 < 8; ++j2) {
      Bs[0][(0 * 66 + bcg + 1 + j2) * 34 + bch] = u0.h[j2];
      Bs[0][(1 * 66 + bcg + 1 + j2) * 34 + bch] = u1.h[j2];
      Bs[0][(2 * 66 + bcg + 1 + j2) * 34 + bch] = u2.h[j2];
    }
  }
  if (nC8 > 1) {
    const u16* cb = inb + (long)(32 + bch) * 4096 + bcg;
    tb0 = (h0 - 1 >= 0) ? *(const uint4*)(cb + (h0 - 1) * 64) : make_uint4(0,0,0,0);
    tb1 = *(const uint4*)(cb + h0 * 64);
    tb2 = (h0 + 1 < 64) ? *(const uint4*)(cb + (h0 + 1) * 64) : make_uint4(0,0,0,0);
  }
  __syncthreads();

  for (int c8 = 0; c8 < nC8; ++c8) {
    const int p = c8 & 1;
    {
      union { uint4 q; u16 h[8]; } u0, u1, u2;
      u0.q = tb0; u1.q = tb1; u2.q = tb2;
      #pragma unroll
      for (int j2 = 0; j2 < 8; ++j2) {
        Bs[p ^ 1][(0 * 66 + bcg + 1 + j2) * 34 + bch] = u0.h[j2];
        Bs[p ^ 1][(1 * 66 + bcg + 1 + j2) * 34 + bch] = u1.h[j2];
        Bs[p ^ 1][(2 * 66 + bcg + 1 + j2) * 34 + bch] = u2.h[j2];
      }
    }
    int c8n = c8 + 2; if (c8n >= nC8) c8n = 0;
    {
      const u16* cb = inb + (long)(c8n * 32 + bch) * 4096 + bcg;
      uint4 n0_ = (h0 - 1 >= 0) ? *(const uint4*)(cb + (h0 - 1) * 64) : make_uint4(0,0,0,0);
      uint4 n1_ = *(const uint4*)(cb + h0 * 64);
      uint4 n2_ = (h0 + 1 < 64) ? *(const uint4*)(cb + (h0 + 1) * 64) : make_uint4(0,0,0,0);
      const u16* wc8 = wlane + (long)c8 * 9 * 256 * 32;
      #pragma unroll
      for (int dy = 0; dy < 3; ++dy) {
        #pragma unroll
        for (int dx = 0; dx < 3; ++dx) {
          const int tap = dy * 3 + dx;
          const u16* wl = wc8 + (long)tap * 256 * 32;
          uint4 af0 = *(const uint4*)(wl);
          uint4 af1 = *(const uint4*)(wl + 16 * 32);
          uint4 af2 = *(const uint4*)(wl + 32 * 32);
          uint4 af3 = *(const uint4*)(wl + 48 * 32);
          bf16x8 bv = *(const bf16x8*)&Bs[p][(dy * 66 + wn + dx + lr) * 34 + lq * 8];
          acc[0] = __builtin_amdgcn_mfma_f32_16x16x32_bf16(*(const bf16x8*)&af0, bv, acc[0], 0, 0, 0);
          acc[1] = __builtin_amdgcn_mfma_f32_16x16x32_bf16(*(const bf16x8*)&af1, bv, acc[1], 0, 0, 0);
          acc[2] = __builtin_amdgcn_mfma_f32_16x16x32_bf16(*(const bf16x8*)&af2, bv, acc[2], 0, 0, 0);
          acc[3] = __builtin_amdgcn_mfma_f32_16x16x32_bf16(*(const bf16x8*)&af3, bv, acc[3], 0, 0, 0);
        }
      }
      tb0 = n0_; tb1 = n1_; tb2 = n2_;
    }
    __syncthreads();
  }
  u16* ob = Out + (long)b * oBS;
  const int n0 = h0 * 64;
  #pragma unroll
  for (int i = 0; i < 4; ++i) {
    #pragma unroll
    for (int r = 0; r < 4; ++r) {
      int ol = i * 16 + lq * 4 + r;
      float al = albe[ol][0], be = albe[ol][1];
      float vv = silu_(acc[i][r] * al + be);
      ob[(long)(o0 + ol) * 4096 + n0 + wn + lr] = f2b(vv);
    }
  }
}

// ---------------- fused chained maxpools: x1 -> mp5 -> mp9 -> mp13 (bf16, in-LDS) ----------------
__global__ __launch_bounds__(256) void pool3(u16* __restrict__ cat, long bs) {
  __shared__ float A[68][72];
  __shared__ float Bb[68][72];
  const int t = threadIdx.x;
  const int c = blockIdx.x, b = blockIdx.y;
  u16* base = cat + (long)b * bs + (long)c * 4096;
  for (int i = t; i < 68 * 72; i += 256) { (&A[0][0])[i] = -1e30f; (&Bb[0][0])[i] = -1e30f; }
  __syncthreads();
  const int r = t >> 2, c0 = (t & 3) * 16;
  #pragma unroll
  for (int j = 0; j < 16; ++j) A[r + 2][c0 + 2 + j] = b2f(base[r * 64 + c0 + j]);
  const long CNu = 1048576;
  #pragma unroll 1
  for (int s = 1; s <= 3; ++s) {
    __syncthreads();
    #pragma unroll
    for (int j = 0; j < 16; ++j) {
      int cc = c0 + j;
      float m = fmaxf(fmaxf(fmaxf(A[r+2][cc], A[r+2][cc+1]), fmaxf(A[r+2][cc+2], A[r+2][cc+3])), A[r+2][cc+4]);
      Bb[r + 2][cc + 2] = m;
    }
    __syncthreads();
    u16* out = base + (long)s * CNu;
    #pragma unroll
    for (int j = 0; j < 16; ++j) {
      int hc = c0 + 2 + j;
      float m = fmaxf(fmaxf(fmaxf(Bb[r][hc], Bb[r+1][hc]), fmaxf(Bb[r+2][hc], Bb[r+3][hc])), Bb[r+4][hc]);
      out[r * 64 + c0 + j] = f2b_trunc(m);
      A[r + 2][hc] = m;
    }
  }
}

// ---------------- PAM row-max via MFMA (qkT: [b][4096][64]) ----------------
// double-buffered Ks + named-reg prefetch -> ONE barrier per iteration.
__global__ __launch_bounds__(256) void pam_qk_max(const u16* __restrict__ qkT, float* __restrict__ pmax) {
  __shared__ u16 Qs[32 * 40];
  __shared__ u16 Ks[2][64 * 40];
  __shared__ float red[4][32][17];
  const int t = threadIdx.x;
  const int b = blockIdx.z, ms = blockIdx.y, n0 = blockIdx.x * 32;
  const int w = t >> 6, l = t & 63, lq = l >> 4, lr = l & 15;
  const int wn = w & 1, wc = w >> 1;
  if (t < 128) {
    int row = t >> 2, cq = (t & 3) * 8;
    *(uint4*)&Qs[row * 40 + cq] = *(const uint4*)(qkT + ((long)b * 4096 + n0 + row) * 64 + cq);
  }
  const int krow = t >> 2, kcq = (t & 3) * 8;
  const u16* kb = qkT + ((long)b * 4096 + krow) * 64 + 32 + kcq;
  {
    uint4 k0 = *(const uint4*)(kb + (long)(ms * 1024) * 64);
    *(uint4*)&Ks[0][krow * 40 + kcq] = k0;
  }
  uint4 kreg = *(const uint4*)(kb + (long)(ms * 1024 + 64) * 64);
  __syncthreads();
  bf16x8 qf = *(const bf16x8*)&Qs[(wn * 16 + lr) * 40 + lq * 8];
  float mx4[4] = {-1e30f, -1e30f, -1e30f, -1e30f};
  for (int it = 0; it < 16; ++it) {
    const int p = it & 1;
    *(uint4*)&Ks[p ^ 1][krow * 40 + kcq] = kreg;     // stage it+1
    int itn = it + 2; if (itn >= 16) itn = 0;        // wrapped dummy
    kreg = *(const uint4*)(kb + (long)(ms * 1024 + itn * 64) * 64);
    #pragma unroll
    for (int s = 0; s < 2; ++s) {
      int msub = wc * 2 + s;
      bf16x8 kf = *(const bf16x8*)&Ks[p][(msub * 16 + lr) * 40 + lq * 8];
      f32x4 S = {};
      S = __builtin_amdgcn_mfma_f32_16x16x32_bf16(qf, kf, S, 0, 0, 0);
      #pragma unroll
      for (int r = 0; r < 4; ++r) mx4[r] = fmaxf(mx4[r], S[r]);
    }
    __syncthreads();   // Ks[p^1] visible for next iter
  }
  #pragma unroll
  for (int r = 0; r < 4; ++r) red[w][wn * 16 + lq * 4 + r][lr] = mx4[r];
  __syncthreads();
  if (t < 32) {
    int wbase = t >> 4;
    float M = -1e30f;
    #pragma unroll
    for (int j = 0; j < 2; ++j)
      #pragma unroll
      for (int l2 = 0; l2 < 16; ++l2)
        M = fmaxf(M, red[wbase + 2 * j][t][l2]);
    pmax[((long)ms * 2 + b) * 4096 + n0 + t] = M;
  }
}

__global__ __launch_bounds__(256) void pam_merge(const float* __restrict__ pmax, float* __restrict__ rmx) {
  int i = blockIdx.x * 256 + threadIdx.x;
  int b = i >> 12, n = i & 4095;
  float m = pmax[(long)b * 4096 + n];
  #pragma unroll
  for (int ms = 1; ms < 4; ++ms) m = fmaxf(m, pmax[((long)ms * 2 + b) * 4096 + n]);
  rmx[i] = m;
}

// ---------------- PAM attention: m-split x2, un-normalized partials ----------------
// v7 (best measured): Qs+Ks LDS staging (coalesced cooperative loads), Ps double-buffer
// -> ONE barrier per 64-m tile; V from swizzled layout in named regs; setprio on PV.
__global__ __launch_bounds__(512) void pam_attn(const u16* __restrict__ qkT,
    const u16* __restrict__ vb, const float* __restrict__ rowmax,
    float* __restrict__ Obase, float* __restrict__ Sbase) {
  __shared__ u16 Qs[32 * 40];
  __shared__ u16 Ks[2][64 * 40];
  __shared__ u16 Ps[2][32 * 72];
  __shared__ float rmL[32];
  __shared__ float srow[32];
  const int t = threadIdx.x;
  const int mh = blockIdx.y;
  const int b = blockIdx.z;
  const int n0 = blockIdx.x * 32;
  const int w = t >> 6, l = t & 63, lq = l >> 4, lr = l & 15;
  const int nf = w & 1;
  const int mf = w >> 1;
  const int cw = w * 32;
  float* O = Obase + (long)mh * 2097152;
  float* S = Sbase + (long)mh * 8192;
  if (t < 128) {
    int row = t >> 2, cq = (t & 3) * 8;
    *(uint4*)&Qs[row * 40 + cq] = *(const uint4*)(qkT + ((long)b * 4096 + n0 + row) * 64 + cq);
  }
  if (t < 32) { rmL[t] = rowmax[(long)b * 4096 + n0 + t] * LOG2E; srow[t] = 0.f; }
  const int krow = t >> 3, kc4 = (t & 7) * 4;
  const u16* kbase = qkT + ((long)b * 4096 + krow) * 64 + 32 + kc4;
  const u16* vop = vb + (long)b * 1048576 + (cw + lr) * 32 + lq * 8;
  const int mStart = mh * 2048, mEnd = mStart + 2048;

  {
    uint2 k0 = *(const uint2*)(kbase + (long)mStart * 64);
    *(uint2*)&Ks[0][krow * 40 + kc4] = k0;
  }
  uint2 kreg = *(const uint2*)(kbase + (long)(mStart + 64) * 64);
  long vt0 = (long)(mStart >> 5) * 8192;
  uint4 vA00 = *(const uint4*)(vop + vt0);
  uint4 vA01 = *(const uint4*)(vop + vt0 + 512);
  uint4 vA10 = *(const uint4*)(vop + vt0 + 8192);
  uint4 vA11 = *(const uint4*)(vop + vt0 + 8704);
  uint4 vB00, vB01, vB10, vB11;

  __syncthreads();
  bf16x8 qf = *(const bf16x8*)&Qs[(nf * 16 + lr) * 40 + lq * 8];
  const float rml = rmL[nf * 16 + lr];
  float spl = 0.f;
  f32x4 acc[2][2] = {};

#define QK_PHASE(KBUF, PBUF)                                                   \
  {                                                                            \
    bf16x8 kf = *(const bf16x8*)&Ks[KBUF][(mf * 16 + lr) * 40 + lq * 8];       \
    f32x4 Sv = {};                                                             \
    Sv = __builtin_amdgcn_mfma_f32_16x16x32_bf16(kf, qf, Sv, 0, 0, 0);         \
    union { u16 h[4]; uint2 q; } pk;                                           \
    _Pragma("unroll")                                                          \
    for (int r = 0; r < 4; ++r) {                                              \
      float p = exp2f(Sv[r] * LOG2E - rml);                                    \
      spl += p;                                                                \
      pk.h[r] = f2b_trunc(p);                                                  \
    }                                                                          \
    *(uint2*)&Ps[PBUF][(nf * 16 + lr) * 72 + mf * 16 + lq * 4] = pk.q;         \
  }

#define PV_PHASE(PBUF, V00, V01, V10, V11)                                     \
  {                                                                            \
    bf16x8 pf0 = *(const bf16x8*)&Ps[PBUF][lr * 72 + lq * 8];                  \
    bf16x8 pf1 = *(const bf16x8*)&Ps[PBUF][(16 + lr) * 72 + lq * 8];           \
    acc[0][0] = __builtin_amdgcn_mfma_f32_16x16x32_bf16(*(bf16x8*)&V00, pf0, acc[0][0], 0, 0, 0); \
    acc[0][1] = __builtin_amdgcn_mfma_f32_16x16x32_bf16(*(bf16x8*)&V00, pf1, acc[0][1], 0, 0, 0); \
    acc[1][0] = __builtin_amdgcn_mfma_f32_16x16x32_bf16(*(bf16x8*)&V01, pf0, acc[1][0], 0, 0, 0); \
    acc[1][1] = __builtin_amdgcn_mfma_f32_16x16x32_bf16(*(bf16x8*)&V01, pf1, acc[1][1], 0, 0, 0); \
    pf0 = *(const bf16x8*)&Ps[PBUF][lr * 72 + 32 + lq * 8];                    \
    pf1 = *(const bf16x8*)&Ps[PBUF][(16 + lr) * 72 + 32 + lq * 8];             \
    acc[0][0] = __builtin_amdgcn_mfma_f32_16x16x32_bf16(*(bf16x8*)&V10, pf0, acc[0][0], 0, 0, 0); \
    acc[0][1] = __builtin_amdgcn_mfma_f32_16x16x32_bf16(*(bf16x8*)&V10, pf1, acc[0][1], 0, 0, 0); \
    acc[1][0] = __builtin_amdgcn_mfma_f32_16x16x32_bf16(*(bf16x8*)&V11, pf0, acc[1][0], 0, 0, 0); \
    acc[1][1] = __builtin_amdgcn_mfma_f32_16x16x32_bf16(*(bf16x8*)&V11, pf1, acc[1][1], 0, 0, 0); \
  }

  #pragma unroll 1
  for (int m0 = mStart; m0 < mEnd; m0 += 128) {
    int m2 = m0 + 128; if (m2 >= mEnd) m2 = mStart;
    int m3 = m0 + 192; if (m3 >= mEnd) m3 = mStart;
    // ---- half A: tile m0 (K in Ks[0], V in vA, P -> Ps[0]) ----
    QK_PHASE(0, 0)
    *(uint2*)&Ks[1][krow * 40 + kc4] = kreg;
    kreg = *(const uint2*)(kbase + (long)m2 * 64);
    {
      long vt = (long)((m0 + 64) >> 5) * 8192;
      vB00 = *(const uint4*)(vop + vt);
      vB01 = *(const uint4*)(vop + vt + 512);
      vB10 = *(const uint4*)(vop + vt + 8192);
      vB11 = *(const uint4*)(vop + vt + 8704);
    }
    __syncthreads();             // Ps[0] + Ks[1] visible
    __builtin_amdgcn_s_setprio(1);
    PV_PHASE(0, vA00, vA01, vA10, vA11)
    __builtin_amdgcn_s_setprio(0);
    // ---- half B: tile m0+64 (K in Ks[1], V in vB, P -> Ps[1]); no barrier between ----
    QK_PHASE(1, 1)
    *(uint2*)&Ks[0][krow * 40 + kc4] = kreg;
    kreg = *(const uint2*)(kbase + (long)m3 * 64);
    {
      long vt = (long)(m2 >> 5) * 8192;
      vA00 = *(const uint4*)(vop + vt);
      vA01 = *(const uint4*)(vop + vt + 512);
      vA10 = *(const uint4*)(vop + vt + 8192);
      vA11 = *(const uint4*)(vop + vt + 8704);
    }
    __syncthreads();             // Ps[1] + Ks[0] visible
    __builtin_amdgcn_s_setprio(1);
    PV_PHASE(1, vB00, vB01, vB10, vB11)
    __builtin_amdgcn_s_setprio(0);
  }
#undef QK_PHASE
#undef PV_PHASE

  spl += __shfl_xor(spl, 16);
  spl += __shfl_xor(spl, 32);
  if (l < 16) atomicAdd(&srow[nf * 16 + lr], spl);
  __syncthreads();
  if (t < 32) S[(long)b * 4096 + n0 + t] = srow[t];
  float* ob = O + (long)b * 1048576 + n0;
  #pragma unroll
  for (int cf = 0; cf < 2; ++cf) {
    #pragma unroll
    for (int r = 0; r < 4; ++r) {
      int c = cw + cf * 16 + lq * 4 + r;
      ob[(long)c * 4096 + lr]      = acc[cf][0][r];
      ob[(long)c * 4096 + 16 + lr] = acc[cf][1][r];
    }
  }
}

// ---------------- CAM ----------------

__global__ __launch_bounds__(256) void fillz(float* __restrict__ p, int n) {
  int i = blockIdx.x * 256 + threadIdx.x;
  if (i < n) p[i] = 0.f;
}

// e[b,c,d] += sum over this block's K slice (split-K x16)
// double-buffered Bs -> ONE barrier per K-step; A direct-from-global.
__global__ __launch_bounds__(256) void cam_e_mfma(const u16* __restrict__ resb, float* __restrict__ e) {
  __shared__ u16 Bs[2][128 * 40];
  const int t = threadIdx.x;
  const int d0 = blockIdx.x * 128;
  const int c0 = blockIdx.y * 64;
  const int bz = blockIdx.z;
  const int b = bz >> 4, ks = bz & 15;
  const int w = t >> 6, l = t & 63, lq = l >> 4, lr = l & 15;
  const int wo = (w >> 1) * 32, wn = (w & 1) * 64;
  const u16* fb = resb + (long)b * 1048576;
  const u16* a0p = fb + (long)(c0 + wo + lr) * 4096 + lq * 8;
  const u16* a1p = a0p + (long)16 * 4096;
  const int bo = t >> 1, bkq = (t & 1) * 16;
  const u16* bp = fb + (long)(d0 + bo) * 4096 + bkq;
  const int kS = ks * 256, kE = kS + 256;
  f32x4 acc[2][4] = {};
  uint4 b0 = *(const uint4*)(bp + kS);
  uint4 b1 = *(const uint4*)(bp + kS + 8);
  *(uint4*)&Bs[0][bo * 40 + bkq] = b0;
  *(uint4*)&Bs[0][bo * 40 + bkq + 8] = b1;
  b0 = *(const uint4*)(bp + kS + 32);
  b1 = *(const uint4*)(bp + kS + 40);
  uint4 a0 = *(const uint4*)(a0p + kS);
  uint4 a1 = *(const uint4*)(a1p + kS);
  __syncthreads();
  for (int kc = kS; kc < kE; kc += 32) {
    const int p = ((kc - kS) >> 5) & 1;
    *(uint4*)&Bs[p ^ 1][bo * 40 + bkq] = b0;
    *(uint4*)&Bs[p ^ 1][bo * 40 + bkq + 8] = b1;
    int kn = kc + 32; if (kn >= kE) kn = kS;
    int kb = kc + 64; if (kb >= kE) kb = kS;
    uint4 a0n = *(const uint4*)(a0p + kn);
    uint4 a1n = *(const uint4*)(a1p + kn);
    uint4 b0n = *(const uint4*)(bp + kb);
    uint4 b1n = *(const uint4*)(bp + kb + 8);
    #pragma unroll
    for (int j = 0; j < 4; ++j) {
      bf16x8 bfv = *(const bf16x8*)&Bs[p][(wn + j * 16 + lr) * 40 + lq * 8];
      acc[0][j] = __builtin_amdgcn_mfma_f32_16x16x32_bf16(*(const bf16x8*)&a0, bfv, acc[0][j], 0, 0, 0);
      acc[1][j] = __builtin_amdgcn_mfma_f32_16x16x32_bf16(*(const bf16x8*)&a1, bfv, acc[1][j], 0, 0, 0);
    }
    a0 = a0n; a1 = a1n; b0 = b0n; b1 = b1n;
    __syncthreads();
  }
  #pragma unroll
  for (int i = 0; i < 2; ++i)
    #pragma unroll
    for (int r = 0; r < 4; ++r) {
      int ol = wo + i * 16 + lq * 4 + r;
      #pragma unroll
      for (int j = 0; j < 4; ++j)
        atomicAdd(&e[((long)b << 16) + (long)(c0 + ol) * 256 + d0 + wn + j * 16 + lr], acc[i][j][r]);
    }
}

__global__ __launch_bounds__(256) void cam_softmax(const float* __restrict__ e, u16* __restrict__ attn) {
  __shared__ float red[256];
  int c = blockIdx.x, b = blockIdx.y, t = threadIdx.x;
  const float* row = e + ((long)b << 16) + (long)c * 256;
  float v = row[t];
  red[t] = v; __syncthreads();
  for (int s = 128; s > 0; s >>= 1) { if (t < s) red[t] = fminf(red[t], red[t + s]); __syncthreads(); }
  float emin = red[0]; __syncthreads();
  float ex = exp2f(LOG2E * (emin - v));
  red[t] = ex; __syncthreads();
  for (int s = 128; s > 0; s >>= 1) { if (t < s) red[t] += red[t + s]; __syncthreads(); }
  float inv = 1.f / red[0];
  attn[((long)b << 16) + (long)c * 256 + t] = f2b(ex * inv);
}

// ---------------- final combine (fuses PAM partial merge) ----------------

__global__ __launch_bounds__(256) void combine(const float* __restrict__ res, const float* __restrict__ O,
    const float* __restrict__ S, const float* __restrict__ cam, const float* __restrict__ gp,
    void* __restrict__ outp, const float* __restrict__ flagp) {
  int idx = blockIdx.x * 256 + threadIdx.x;
  int b = idx >> 20, n = idx & 4095;
  float g1 = gp[0], g2 = gp[1];
  float sden = S[(long)b * 4096 + n] + S[8192 + (long)b * 4096 + n];
  float pamv = (O[idx] + O[2097152 + idx]) / sden;
  float v = 3.f * res[idx] + g1 * pamv + g2 * cam[idx];
  if (*flagp > 0.5f) ((float*)outp)[idx] = v;
  else               ((u16*)outp)[idx] = f2b(v);
}

// ---------------- launch ----------------

extern "C" void kernel_launch(void* const* d_in, const int* in_sizes, int n_in,
                              void* d_out, int out_size, void* d_ws, size_t ws_size,
                              hipStream_t stream)
{
  (void)out_size; (void)ws_size; (void)n_in;
  float* ws = (float*)d_ws;
  const long CN = 1048576;   // 256*4096

  float* A  = ws;            // r bf16 -> res fp32
  float* Bp = ws + 2 * CN;   // xf fp32 -> s3out/s5out/resb bf16
  float* Cp = ws + 4 * CN;   // CoordAtt smalls -> s1out bf16 -> vb bf16 (V-swizzled)
  float* D  = ws + 6 * CN;   // cat(8CN u16) -> y12 -> {attn smalls} -> cam; O0/O1 at +4CN
  const long WFo = 14 * CN;

  u16*   rB   = (u16*)A;
  float* res  = A;
  float* xf   = Bp;
  u16*   BpU  = (u16*)Bp;
  float* yin  = Cp;
  float* ybn  = Cp + 65536;
  u16*   CpU  = (u16*)Cp;
  u16*   catU = (u16*)D;
  u16*   y12U = (u16*)D;
  float* D2   = D + 2 * CN;
  u16*   qkTU = (u16*)(D2 + 262144);
  float* pmax = D2 + 524288;
  float* rmx  = D2 + 557056;
  float* e    = D2 + 565248;
  u16*   attnc= (u16*)(D2 + 696320);
  float* S0   = D2 + 761856;
  float* cam  = D;
  float* O0   = D + 4 * CN;

  ConvArgs ca;
  long fOff[30], hOff[30];
  long hcur = 0;
  float* flagp = ws + WFo;
  {
    long cum = 0, fcur = WFo + 4;
    for (int i = 0; i < 30; ++i) {
      ca.src[i] = d_in[i];
      int h = (i == 8 || i == 10 || i == 14 || i == 16 || i == 20 ||
               i == 22 || i == 24 || i == 26) ? 1 : 0;
      ca.mode[i] = h;
      if (i == 0) { ca.dst[i] = 2 * CN; fOff[i] = 2 * CN; }
      else if (h) { ca.dst[i] = hcur; hOff[i] = hcur; hcur += in_sizes[i]; }
      else        { ca.dst[i] = fcur; fOff[i] = fcur; fcur += in_sizes[i]; }
      cum += in_sizes[i];
      ca.end[i] = (int)cum;
    }
  }
  long fTotal = WFo + 4;
  for (int i = 1; i < 30; ++i) if (!ca.mode[i]) fTotal = (fOff[i] + in_sizes[i] > fTotal) ? fOff[i] + in_sizes[i] : fTotal;
  u16* wsH = (u16*)(ws + fTotal);
  u16* wt3a = wsH + hcur;
  u16* wt3b = wsH + hcur + 589824;
  int total = ca.end[29];

  detect_k<<<dim3(1), dim3(128), 0, stream>>>((const u16*)d_in[0], flagp);
  convert_all<<<dim3((total + 255) / 256), dim3(256), 0, stream>>>(ca, ws, wsH, flagp, total);

  float* ca_w1 = ws + fOff[1];
  float* ca_b1 = ws + fOff[2];
  float* ca_bn = ws + fOff[3];
  float* ca_wh = ws + fOff[4];
  float* ca_bh = ws + fOff[5];
  float* ca_ww = ws + fOff[6];
  float* ca_bw = ws + fOff[7];
  u16*   s1_w  = wsH + hOff[8];   float* s1_bn = ws + fOff[9];
  u16*   s2_w  = wsH + hOff[10];  float* s2_bn = ws + fOff[11];
  float* s3_wf = ws + fOff[12];   float* s3_bn = ws + fOff[13];
  u16*   s4_w  = wsH + hOff[14];  float* s4_bn = ws + fOff[15];
  u16*   s5_w  = wsH + hOff[16];  float* s5_bn = ws + fOff[17];
  float* s6_wf = ws + fOff[18];   float* s6_bn = ws + fOff[19];
  u16*   s7_w  = wsH + hOff[20];  float* s7_bn = ws + fOff[21];
  u16*   qk_w  = wsH + hOff[22];  float* qk_b  = ws + fOff[23];
  u16*   pv_w  = wsH + hOff[26];  float* pv_b  = ws + fOff[27];
  float* gammas = ws + fOff[28];

  w3t<<<dim3(2304), dim3(256), 0, stream>>>(s3_wf, wt3a);
  w3t<<<dim3(2304), dim3(256), 0, stream>>>(s6_wf, wt3b);

  // ---- CoordAtt ----
  plane_means<<<dim3(512), dim3(256), 0, stream>>>(xf, yin);
  ca_conv1<<<dim3(2, 8), dim3(128), 0, stream>>>(yin, ca_w1, ca_b1, ca_bn, ybn);
  apply_ca<<<dim3(8192), dim3(256), 0, stream>>>(xf, ybn, ca_wh, ca_bh, ca_ww, ca_bw, rB);

  // ---- SPPCSPC (bf16 activations) ----
  mfma_cbs<1,1><<<dim3(64, 4, 2), dim3(256), 0, stream>>>(s1_w, 0, rB, CN, CpU, CN, 256, 256, 4096, s1_bn, nullptr, nullptr);
  conv3_mfma<<<dim3(64, 4, 2), dim3(256), 0, stream>>>(wt3a, CpU, CN, BpU, CN, 256, 256, s3_bn);
  mfma_cbs<1,1><<<dim3(64, 4, 2), dim3(256), 0, stream>>>(s4_w, 0, BpU, CN, catU, 4 * CN, 256, 256, 4096, s4_bn, nullptr, nullptr);

  pool3<<<dim3(256, 2), dim3(256), 0, stream>>>(catU, 4 * CN);

  mfma_cbs<1,1><<<dim3(64, 4, 2), dim3(256), 0, stream>>>(s5_w, 0, catU, 4 * CN, BpU, CN, 256, 1024, 4096, s5_bn, nullptr, nullptr);
  conv3_mfma<<<dim3(64, 4, 2), dim3(256), 0, stream>>>(wt3b, BpU, CN, y12U, 2 * CN, 256, 256, s6_bn);
  mfma_cbs<1,1><<<dim3(64, 4, 2), dim3(256), 0, stream>>>(s2_w, 0, rB, CN, y12U + CN, 2 * CN, 256, 256, 4096, s2_bn, nullptr, nullptr);
  // s7: dual-write fp32 res + bf16 resb (fuses cvtb)
  mfma_cbs<1,4><<<dim3(64, 4, 2), dim3(256), 0, stream>>>(s7_w, 0, y12U, 2 * CN, res, CN, 256, 512, 4096, s7_bn, nullptr, BpU);

  // ---- PAM ----
  // qk: write qkT [n][64] directly (fuses transpose_hh)
  mfma_cbs<0,3><<<dim3(64, 1, 2), dim3(256), 0, stream>>>(qk_w, 0, BpU, CN, qkTU, 262144, 64, 256, 4096, nullptr, qk_b, nullptr);
  mfma_cbs<0,2><<<dim3(64, 4, 2), dim3(256), 0, stream>>>(pv_w, 0, BpU, CN, CpU, CN, 256, 256, 4096, nullptr, pv_b, nullptr);

  pam_qk_max<<<dim3(128, 4, 2), dim3(256), 0, stream>>>(qkTU, pmax);
  pam_merge<<<dim3(32), dim3(256), 0, stream>>>(pmax, rmx);
  pam_attn<<<dim3(128, 2, 2), dim3(512), 0, stream>>>(qkTU, CpU, rmx, O0, S0);

  // ---- CAM ----
  fillz<<<dim3(512), dim3(256), 0, stream>>>(e, 131072);
  cam_e_mfma<<<dim3(2, 4, 32), dim3(256), 0, stream>>>(BpU, e);
  cam_softmax<<<dim3(256, 2), dim3(256), 0, stream>>>(e, attnc);
  mfma_cbs<0,0><<<dim3(64, 4, 2), dim3(256), 0, stream>>>(attnc, 65536, BpU, CN, cam, CN, 256, 256, 4096, nullptr, nullptr, nullptr);

  // ---- combine ----
  combine<<<dim3(8192), dim3(256), 0, stream>>>(res, O0, S0, cam, gammas, d_out, flagp);
}

// Round 12
// 409.253 us; speedup vs baseline: 1.0403x; 1.0403x over previous
//
#include <hip/hip_runtime.h>

typedef unsigned short u16;
typedef __attribute__((ext_vector_type(8))) short bf16x8;
typedef __attribute__((ext_vector_type(4))) float f32x4;
#define EPSV 1e-5f
#define LOG2E 1.4426950408889634f

__device__ __forceinline__ float b2f(u16 u) {
  union { float f; unsigned int i; } v; v.i = ((unsigned int)u) << 16; return v.f;
}
__device__ __forceinline__ u16 f2b(float f) {
  union { float f; unsigned int i; } v; v.f = f;
  unsigned int r = v.i + 0x7FFFu + ((v.i >> 16) & 1u);
  return (u16)(r >> 16);
}
__device__ __forceinline__ u16 f2b_trunc(float f) {
  union { float f; unsigned int i; } v; v.f = f;
  return (u16)(v.i >> 16);
}
__device__ __forceinline__ float silu_(float z) { return z / (1.f + exp2f(-LOG2E * z)); }

// ---------------- dtype detect ----------------
__global__ __launch_bounds__(128) void detect_k(const u16* __restrict__ xp, float* __restrict__ flag) {
  __shared__ int cnt[2];
  int t = threadIdx.x;
  if (t < 2) cnt[t] = 0;
  __syncthreads();
  u16 u = xp[t * 2];
  int e = (u >> 7) & 0xff;
  if (e != 0 && (e < 90 || e > 160)) atomicAdd(&cnt[0], 1);
  if (u == 0) atomicAdd(&cnt[1], 1);
  __syncthreads();
  if (t == 0) *flag = (cnt[0] > 16 || cnt[1] > 64) ? 1.f : 0.f;
}

// ---------------- input conversion ----------------

struct ConvArgs {
  const void* src[30];
  long dst[30];
  int end[30];
  int mode[30];
};

__global__ __launch_bounds__(256) void convert_all(ConvArgs a, float* __restrict__ wsF,
                                                   u16* __restrict__ wsH,
                                                   const float* __restrict__ flagp, int total) {
  const int flag = (*flagp > 0.5f);
  int gid = blockIdx.x * 256 + threadIdx.x;
  if (gid >= total) return;
  #pragma unroll 1
  for (int s = 0; s < 30; ++s) {
    if (gid < a.end[s]) {
      int idx = gid - (s ? a.end[s - 1] : 0);
      if (a.mode[s] == 0) {
        float v = flag ? ((const float*)a.src[s])[idx] : b2f(((const u16*)a.src[s])[idx]);
        wsF[a.dst[s] + idx] = v;
      } else {
        u16 h = flag ? f2b(((const float*)a.src[s])[idx]) : ((const u16*)a.src[s])[idx];
        wsH[a.dst[s] + idx] = h;
      }
      return;
    }
  }
}

// conv3 weight transform: fp32 W[o][I][3][3] -> bf16 Wt[I/32][tap][256o][32ch]
__global__ __launch_bounds__(256) void w3t(const float* __restrict__ Wsrc, u16* __restrict__ Wdst) {
  int idx = blockIdx.x * 256 + threadIdx.x;
  int ch = idx & 31;
  int o  = (idx >> 5) & 255;
  int tap = (idx >> 13) % 9;
  int c8 = (idx >> 13) / 9;
  int i = c8 * 32 + ch;
  Wdst[idx] = f2b(Wsrc[((long)o * 256 + i) * 9 + tap]);
}

// ---------------- CoordAtt ----------------

__global__ __launch_bounds__(256) void plane_means(const float* __restrict__ x, float* __restrict__ yin) {
  __shared__ float pl[4096];
  int bc = blockIdx.x, t = threadIdx.x;
  const float* xp = x + (long)bc * 4096;
  for (int j = 0; j < 16; ++j) { int id = j * 256 + t; pl[id] = xp[id]; }
  __syncthreads();
  if (t < 64) {
    float s = 0.f;
    for (int w = 0; w < 64; ++w) s += pl[t * 64 + w];
    yin[(long)bc * 128 + t] = s * (1.f / 64.f);
  } else if (t < 128) {
    int w = t - 64; float s = 0.f;
    for (int h = 0; h < 64; ++h) s += pl[h * 64 + w];
    yin[(long)bc * 128 + 64 + w] = s * (1.f / 64.f);
  }
}

// grid (2 b x 8 o)
__global__ __launch_bounds__(128) void ca_conv1(const float* __restrict__ yin, const float* __restrict__ w1,
                                                const float* __restrict__ b1, const float* __restrict__ bnp,
                                                float* __restrict__ ybn) {
  int b = blockIdx.x, o = blockIdx.y, p = threadIdx.x;
  float acc = 0.f;
  for (int c = 0; c < 256; ++c)
    acc += w1[o * 256 + c] * yin[((long)b * 256 + c) * 128 + p];
  float z = acc + b1[o];
  float g = bnp[o], bt = bnp[8 + o], mn = bnp[16 + o], vr = bnp[24 + o];
  float s = g * rsqrtf(vr + EPSV);
  z = z * s + (bt - mn * s);
  float hs = fminf(fmaxf(z + 3.f, 0.f), 6.f) * (1.f / 6.f);
  ybn[((long)b * 8 + o) * 128 + p] = z * hs;
}

// ca_gate fused: recompute the two sigmoids per element (ybn is 2KB, L1-hot)
__global__ __launch_bounds__(256) void apply_ca(const float* __restrict__ x, const float* __restrict__ ybn,
    const float* __restrict__ wh, const float* __restrict__ bh,
    const float* __restrict__ ww, const float* __restrict__ bw,
    u16* __restrict__ r) {
  int idx = blockIdx.x * 256 + threadIdx.x;
  int n = idx & 4095, bc = idx >> 12;
  int b = bc >> 8, c = bc & 255;
  int h = n >> 6, w = n & 63;
  const float* yb = ybn + (long)b * 1024;   // [8][128]
  float d1 = bh[c], d2 = bw[c];
  #pragma unroll
  for (int o = 0; o < 8; ++o) {
    d1 += wh[c * 8 + o] * yb[o * 128 + h];
    d2 += ww[c * 8 + o] * yb[o * 128 + 64 + w];
  }
  float ah = 1.f / (1.f + exp2f(-LOG2E * d1));
  float aw = 1.f / (1.f + exp2f(-LOG2E * d2));
  r[idx] = f2b(x[idx] * ah * aw);
}

// ---------------- MFMA 1x1 conv, 64o x 64n tile: bf16 in (BK=32, best measured) -------
// double-buffered Bs -> ONE barrier per K-step; A direct-from-global named regs.
// OUTH: 0 = fp32 linear, 1 = bf16 linear [ch][n], 2 = bf16 V-swizzled [n/32][ch][n%32],
//       3 = bf16 TRANSPOSED [n][64] (fuses transpose_hh), 4 = fp32 + bf16 dual (fuses cvtb)

template<int ACT, int OUTH>
__global__ __launch_bounds__(256) void mfma_cbs(
    const u16* __restrict__ Wbf, long aBS,
    const u16* __restrict__ In, long bBS,
    void* __restrict__ Out, long oBS,
    int O, int K, int N,
    const float* __restrict__ bnp, const float* __restrict__ bias,
    void* __restrict__ Out2)
{
  __shared__ u16 Bs[2][64 * 40];
  __shared__ float albe[64][2];
  const int t = threadIdx.x;
  const int n0 = blockIdx.x * 64;
  const int o0 = blockIdx.y * 64;
  const int b  = blockIdx.z;
  const int w = t >> 6, l = t & 63, lq = l >> 4, lr = l & 15;
  const int wo = (w >> 1) * 32, wn = (w & 1) * 32;
  if (t < 64) {
    int o = o0 + t;
    float al = 1.f, be = 0.f;
    if (bnp) {
      float g = bnp[o], bt = bnp[O + o], mn = bnp[2 * O + o], vr = bnp[3 * O + o];
      al = g * rsqrtf(vr + EPSV); be = bt - mn * al;
    }
    if (bias) be += bias[o];
    albe[t][0] = al; albe[t][1] = be;
  }
  const u16* Ab = Wbf + (long)b * aBS;
  const u16* inb = In + (long)b * bBS + n0;
  const u16* a0p = Ab + (long)(o0 + wo + lr) * K + lq * 8;
  const u16* a1p = a0p + (long)16 * K;
  const int bk = t >> 3, bn8 = (t & 7) * 8;
  f32x4 acc[2][2] = {};
  // prologue: stage Bs[0] (kc=0); prefetch B(kc=32) + A(kc=0)
  uint4 b0 = *(const uint4*)(inb + (long)bk * N + bn8);
  {
    union { uint4 q; u16 h[8]; } tb; tb.q = b0;
    #pragma unroll
    for (int j = 0; j < 8; ++j) Bs[0][(bn8 + j) * 40 + bk] = tb.h[j];
  }
  b0 = *(const uint4*)(inb + (long)(32 + bk) * N + bn8);   // K >= 256 always
  uint4 a0 = *(const uint4*)(a0p);
  uint4 a1 = *(const uint4*)(a1p);
  __syncthreads();
  for (int kc = 0; kc < K; kc += 32) {
    const int p = (kc >> 5) & 1;
    {
      union { uint4 q; u16 h[8]; } tb; tb.q = b0;
      #pragma unroll
      for (int j = 0; j < 8; ++j) Bs[p ^ 1][(bn8 + j) * 40 + bk] = tb.h[j];
    }
    int kn = kc + 32; if (kn >= K) kn = 0;
    int kb = kc + 64; if (kb >= K) kb = 0;
    uint4 a0n = *(const uint4*)(a0p + kn);
    uint4 a1n = *(const uint4*)(a1p + kn);
    uint4 b0n = *(const uint4*)(inb + (long)(kb + bk) * N + bn8);
    bf16x8 bfv0 = *(const bf16x8*)&Bs[p][(wn + lr) * 40 + lq * 8];
    bf16x8 bfv1 = *(const bf16x8*)&Bs[p][(wn + 16 + lr) * 40 + lq * 8];
    acc[0][0] = __builtin_amdgcn_mfma_f32_16x16x32_bf16(*(const bf16x8*)&a0, bfv0, acc[0][0], 0, 0, 0);
    acc[0][1] = __builtin_amdgcn_mfma_f32_16x16x32_bf16(*(const bf16x8*)&a0, bfv1, acc[0][1], 0, 0, 0);
    acc[1][0] = __builtin_amdgcn_mfma_f32_16x16x32_bf16(*(const bf16x8*)&a1, bfv0, acc[1][0], 0, 0, 0);
    acc[1][1] = __builtin_amdgcn_mfma_f32_16x16x32_bf16(*(const bf16x8*)&a1, bfv1, acc[1][1], 0, 0, 0);
    a0 = a0n; a1 = a1n; b0 = b0n;
    __syncthreads();
  }
  float* ob = (float*)Out + (long)b * oBS;
  u16* obh = (u16*)Out + (long)b * oBS;
  u16* obh2 = Out2 ? (u16*)Out2 + (long)b * oBS : nullptr;
  if (OUTH == 3) {
    #pragma unroll
    for (int i = 0; i < 2; ++i) {
      #pragma unroll
      for (int j = 0; j < 2; ++j) {
        int n = n0 + wn + j * 16 + lr;
        union { u16 h[4]; uint2 q; } pk;
        #pragma unroll
        for (int r = 0; r < 4; ++r) {
          int ol = wo + i * 16 + lq * 4 + r;
          float vv = acc[i][j][r] * albe[ol][0] + albe[ol][1];
          if (ACT) vv = silu_(vv);
          pk.h[r] = f2b(vv);
        }
        *(uint2*)&obh[(long)n * 64 + o0 + wo + i * 16 + lq * 4] = pk.q;
      }
    }
  } else {
    #pragma unroll
    for (int i = 0; i < 2; ++i) {
      #pragma unroll
      for (int r = 0; r < 4; ++r) {
        int ol = wo + i * 16 + lq * 4 + r;
        float al = albe[ol][0], be = albe[ol][1];
        #pragma unroll
        for (int j = 0; j < 2; ++j) {
          float vv = acc[i][j][r] * al + be;
          if (ACT) vv = silu_(vv);
          if (OUTH == 2) {
            int col = n0 + wn + j * 16 + lr;
            obh[((long)(col >> 5) * 256 + (o0 + ol)) * 32 + (col & 31)] = f2b(vv);
          } else if (OUTH == 1) {
            obh[(long)(o0 + ol) * N + n0 + wn + j * 16 + lr] = f2b(vv);
          } else {  // 0 or 4: fp32 linear
            ob[(long)(o0 + ol) * N + n0 + wn + j * 16 + lr] = vv;
            if (OUTH == 4)
              obh2[(long)(o0 + ol) * N + n0 + wn + j * 16 + lr] = f2b(vv);
          }
        }
      }
    }
  }
}

// ---------------- dual GEMM: s1 and s2 in ONE dispatch (same input rB, ACT=1, OUTH=1) --
// grid.y in [0,8): sel = y>>2 picks {W,bn,Out}; o0 = (y&3)*64. K=256, N=4096.
__global__ __launch_bounds__(256) void mfma_cbs_dual(
    const u16* __restrict__ Wa, const u16* __restrict__ Wb,
    const u16* __restrict__ In, long bBS,
    u16* __restrict__ OutA, long oBSa,
    u16* __restrict__ OutB, long oBSb,
    const float* __restrict__ bnA, const float* __restrict__ bnB)
{
  __shared__ u16 Bs[2][64 * 40];
  __shared__ float albe[64][2];
  const int t = threadIdx.x;
  const int n0 = blockIdx.x * 64;
  const int sel = blockIdx.y >> 2;
  const int o0 = (blockIdx.y & 3) * 64;
  const int b  = blockIdx.z;
  const u16* Wbf = sel ? Wb : Wa;
  const float* bnp = sel ? bnB : bnA;
  u16* Out = sel ? OutB : OutA;
  const long oBS = sel ? oBSb : oBSa;
  const int K = 256, N = 4096, O = 256;
  const int w = t >> 6, l = t & 63, lq = l >> 4, lr = l & 15;
  const int wo = (w >> 1) * 32, wn = (w & 1) * 32;
  if (t < 64) {
    int o = o0 + t;
    float g = bnp[o], bt = bnp[O + o], mn = bnp[2 * O + o], vr = bnp[3 * O + o];
    float al = g * rsqrtf(vr + EPSV);
    albe[t][0] = al; albe[t][1] = bt - mn * al;
  }
  const u16* inb = In + (long)b * bBS + n0;
  const u16* a0p = Wbf + (long)(o0 + wo + lr) * K + lq * 8;
  const u16* a1p = a0p + (long)16 * K;
  const int bk = t >> 3, bn8 = (t & 7) * 8;
  f32x4 acc[2][2] = {};
  uint4 b0 = *(const uint4*)(inb + (long)bk * N + bn8);
  {
    union { uint4 q; u16 h[8]; } tb; tb.q = b0;
    #pragma unroll
    for (int j = 0; j < 8; ++j) Bs[0][(bn8 + j) * 40 + bk] = tb.h[j];
  }
  b0 = *(const uint4*)(inb + (long)(32 + bk) * N + bn8);
  uint4 a0 = *(const uint4*)(a0p);
  uint4 a1 = *(const uint4*)(a1p);
  __syncthreads();
  for (int kc = 0; kc < K; kc += 32) {
    const int p = (kc >> 5) & 1;
    {
      union { uint4 q; u16 h[8]; } tb; tb.q = b0;
      #pragma unroll
      for (int j = 0; j < 8; ++j) Bs[p ^ 1][(bn8 + j) * 40 + bk] = tb.h[j];
    }
    int kn = kc + 32; if (kn >= K) kn = 0;
    int kb = kc + 64; if (kb >= K) kb = 0;
    uint4 a0n = *(const uint4*)(a0p + kn);
    uint4 a1n = *(const uint4*)(a1p + kn);
    uint4 b0n = *(const uint4*)(inb + (long)(kb + bk) * N + bn8);
    bf16x8 bfv0 = *(const bf16x8*)&Bs[p][(wn + lr) * 40 + lq * 8];
    bf16x8 bfv1 = *(const bf16x8*)&Bs[p][(wn + 16 + lr) * 40 + lq * 8];
    acc[0][0] = __builtin_amdgcn_mfma_f32_16x16x32_bf16(*(const bf16x8*)&a0, bfv0, acc[0][0], 0, 0, 0);
    acc[0][1] = __builtin_amdgcn_mfma_f32_16x16x32_bf16(*(const bf16x8*)&a0, bfv1, acc[0][1], 0, 0, 0);
    acc[1][0] = __builtin_amdgcn_mfma_f32_16x16x32_bf16(*(const bf16x8*)&a1, bfv0, acc[1][0], 0, 0, 0);
    acc[1][1] = __builtin_amdgcn_mfma_f32_16x16x32_bf16(*(const bf16x8*)&a1, bfv1, acc[1][1], 0, 0, 0);
    a0 = a0n; a1 = a1n; b0 = b0n;
    __syncthreads();
  }
  u16* obh = Out + (long)b * oBS;
  #pragma unroll
  for (int i = 0; i < 2; ++i) {
    #pragma unroll
    for (int r = 0; r < 4; ++r) {
      int ol = wo + i * 16 + lq * 4 + r;
      float al = albe[ol][0], be = albe[ol][1];
      #pragma unroll
      for (int j = 0; j < 2; ++j) {
        float vv = silu_(acc[i][j][r] * al + be);
        obh[(long)(o0 + ol) * N + n0 + wn + j * 16 + lr] = f2b(vv);
      }
    }
  }
}

// ---------------- MFMA 3x3 conv (implicit GEMM), bf16 in/out ----------------
// one output ROW per block (512 blocks = 2/CU); 3-row double-buffered stage ->
// ONE barrier per c8 step; weights direct-from-global; wave = 64o x 16px.
__global__ __launch_bounds__(256) void conv3_mfma(
    const u16* __restrict__ Wt,
    const u16* __restrict__ In, long iBS,
    u16* __restrict__ Out, long oBS, int O, int I,
    const float* __restrict__ bnp)
{
  __shared__ u16 Bs[2][3 * 66 * 34];
  __shared__ float albe[64][2];
  const int t = threadIdx.x;
  const int h0 = blockIdx.x;
  const int o0 = blockIdx.y * 64;
  const int b  = blockIdx.z;
  const int w = t >> 6, l = t & 63, lq = l >> 4, lr = l & 15;
  const int wn = w * 16;
  if (t < 64) {
    int o = o0 + t;
    float g = bnp[o], bt = bnp[O + o], mn = bnp[2 * O + o], vr = bnp[3 * O + o];
    float al = g * rsqrtf(vr + EPSV);
    albe[t][0] = al; albe[t][1] = bt - mn * al;
  }
  if (t < 192) {
    int r = t >> 6, cs = (t >> 5) & 1, ch = t & 31;
    Bs[0][(r * 66 + (cs ? 65 : 0)) * 34 + ch] = 0;
    Bs[1][(r * 66 + (cs ? 65 : 0)) * 34 + ch] = 0;
  }
  const u16* inb = In + (long)b * iBS;
  const int bch = t >> 3, bcg = (t & 7) * 8;
  const u16* wlane = Wt + (long)(o0 + lr) * 32 + lq * 8;
  const int nC8 = I >> 5;
  f32x4 acc[4] = {};

  uint4 tb0, tb1, tb2;
  {
    const u16* cb = inb + (long)bch * 4096 + bcg;
    tb0 = (h0 - 1 >= 0) ? *(const uint4*)(cb + (h0 - 1) * 64) : make_uint4(0,0,0,0);
    tb1 = *(const uint4*)(cb + h0 * 64);
    tb2 = (h0 + 1 < 64) ? *(const uint4*)(cb + (h0 + 1) * 64) : make_uint4(0,0,0,0);
  }
  {
    union { uint4 q; u16 h[8]; } u0, u1, u2;
    u0.q = tb0; u1.q = tb1; u2.q = tb2;
    #pragma unroll
    for (int j2 = 0; j2 < 8; ++j2) {
      Bs[0][(0 * 66 + bcg + 1 + j2) * 34 + bch] = u0.h[j2];
      Bs[0][(1 * 66 + bcg + 1 + j2) * 34 + bch] = u1.h[j2];
      Bs[0][(2 * 66 + bcg + 1 + j2) * 34 + bch] = u2.h[j2];
    }
  }
  if (nC8 > 1) {
    const u16* cb = inb + (long)(32 + bch) * 4096 + bcg;
    tb0 = (h0 - 1 >= 0) ? *(const uint4*)(cb + (h0 - 1) * 64) : make_uint4(0,0,0,0);
    tb1 = *(const uint4*)(cb + h0 * 64);
    tb2 = (h0 + 1 < 64) ? *(const uint4*)(cb + (h0 + 1) * 64) : make_uint4(0,0,0,0);
  }
  __syncthreads();

  for (int c8 = 0; c8 < nC8; ++c8) {
    const int p = c8 & 1;
    {
      union { uint4 q; u16 h[8]; } u0, u1, u2;
      u0.q = tb0; u1.q = tb1; u2.q = tb2;
      #pragma unroll
      for (int j2 = 0; j2 < 8; ++j2) {
        Bs[p ^ 1][(0 * 66 + bcg + 1 + j2) * 34 + bch] = u0.h[j2];
        Bs[p ^ 1][(1 * 66 + bcg + 1 + j2) * 34 + bch] = u1.h[j2];
        Bs[p ^ 1][(2 * 66 + bcg + 1 + j2) * 34 + bch] = u2.h[j2];
      }
    }
    int c8n = c8 + 2; if (c8n >= nC8) c8n = 0;
    {
      const u16* cb = inb + (long)(c8n * 32 + bch) * 4096 + bcg;
      uint4 n0_ = (h0 - 1 >= 0) ? *(const uint4*)(cb + (h0 - 1) * 64) : make_uint4(0,0,0,0);
      uint4 n1_ = *(const uint4*)(cb + h0 * 64);
      uint4 n2_ = (h0 + 1 < 64) ? *(const uint4*)(cb + (h0 + 1) * 64) : make_uint4(0,0,0,0);
      const u16* wc8 = wlane + (long)c8 * 9 * 256 * 32;
      #pragma unroll
      for (int dy = 0; dy < 3; ++dy) {
        #pragma unroll
        for (int dx = 0; dx < 3; ++dx) {
          const int tap = dy * 3 + dx;
          const u16* wl = wc8 + (long)tap * 256 * 32;
          uint4 af0 = *(const uint4*)(wl);
          uint4 af1 = *(const uint4*)(wl + 16 * 32);
          uint4 af2 = *(const uint4*)(wl + 32 * 32);
          uint4 af3 = *(const uint4*)(wl + 48 * 32);
          bf16x8 bv = *(const bf16x8*)&Bs[p][(dy * 66 + wn + dx + lr) * 34 + lq * 8];
          acc[0] = __builtin_amdgcn_mfma_f32_16x16x32_bf16(*(const bf16x8*)&af0, bv, acc[0], 0, 0, 0);
          acc[1] = __builtin_amdgcn_mfma_f32_16x16x32_bf16(*(const bf16x8*)&af1, bv, acc[1], 0, 0, 0);
          acc[2] = __builtin_amdgcn_mfma_f32_16x16x32_bf16(*(const bf16x8*)&af2, bv, acc[2], 0, 0, 0);
          acc[3] = __builtin_amdgcn_mfma_f32_16x16x32_bf16(*(const bf16x8*)&af3, bv, acc[3], 0, 0, 0);
        }
      }
      tb0 = n0_; tb1 = n1_; tb2 = n2_;
    }
    __syncthreads();
  }
  u16* ob = Out + (long)b * oBS;
  const int n0 = h0 * 64;
  #pragma unroll
  for (int i = 0; i < 4; ++i) {
    #pragma unroll
    for (int r = 0; r < 4; ++r) {
      int ol = i * 16 + lq * 4 + r;
      float al = albe[ol][0], be = albe[ol][1];
      float vv = silu_(acc[i][r] * al + be);
      ob[(long)(o0 + ol) * 4096 + n0 + wn + lr] = f2b(vv);
    }
  }
}

// ---------------- fused chained maxpools: x1 -> mp5 -> mp9 -> mp13 (bf16, in-LDS) ----------------
__global__ __launch_bounds__(256) void pool3(u16* __restrict__ cat, long bs) {
  __shared__ float A[68][72];
  __shared__ float Bb[68][72];
  const int t = threadIdx.x;
  const int c = blockIdx.x, b = blockIdx.y;
  u16* base = cat + (long)b * bs + (long)c * 4096;
  for (int i = t; i < 68 * 72; i += 256) { (&A[0][0])[i] = -1e30f; (&Bb[0][0])[i] = -1e30f; }
  __syncthreads();
  const int r = t >> 2, c0 = (t & 3) * 16;
  #pragma unroll
  for (int j = 0; j < 16; ++j) A[r + 2][c0 + 2 + j] = b2f(base[r * 64 + c0 + j]);
  const long CNu = 1048576;
  #pragma unroll 1
  for (int s = 1; s <= 3; ++s) {
    __syncthreads();
    #pragma unroll
    for (int j = 0; j < 16; ++j) {
      int cc = c0 + j;
      float m = fmaxf(fmaxf(fmaxf(A[r+2][cc], A[r+2][cc+1]), fmaxf(A[r+2][cc+2], A[r+2][cc+3])), A[r+2][cc+4]);
      Bb[r + 2][cc + 2] = m;
    }
    __syncthreads();
    u16* out = base + (long)s * CNu;
    #pragma unroll
    for (int j = 0; j < 16; ++j) {
      int hc = c0 + 2 + j;
      float m = fmaxf(fmaxf(fmaxf(Bb[r][hc], Bb[r+1][hc]), fmaxf(Bb[r+2][hc], Bb[r+3][hc])), Bb[r+4][hc]);
      out[r * 64 + c0 + j] = f2b_trunc(m);
      A[r + 2][hc] = m;
    }
  }
}

// ---------------- PAM row-max via MFMA (qkT: [b][4096][64]) ----------------
// double-buffered Ks + named-reg prefetch -> ONE barrier per iteration.
__global__ __launch_bounds__(256) void pam_qk_max(const u16* __restrict__ qkT, float* __restrict__ pmax) {
  __shared__ u16 Qs[32 * 40];
  __shared__ u16 Ks[2][64 * 40];
  __shared__ float red[4][32][17];
  const int t = threadIdx.x;
  const int b = blockIdx.z, ms = blockIdx.y, n0 = blockIdx.x * 32;
  const int w = t >> 6, l = t & 63, lq = l >> 4, lr = l & 15;
  const int wn = w & 1, wc = w >> 1;
  if (t < 128) {
    int row = t >> 2, cq = (t & 3) * 8;
    *(uint4*)&Qs[row * 40 + cq] = *(const uint4*)(qkT + ((long)b * 4096 + n0 + row) * 64 + cq);
  }
  const int krow = t >> 2, kcq = (t & 3) * 8;
  const u16* kb = qkT + ((long)b * 4096 + krow) * 64 + 32 + kcq;
  {
    uint4 k0 = *(const uint4*)(kb + (long)(ms * 1024) * 64);
    *(uint4*)&Ks[0][krow * 40 + kcq] = k0;
  }
  uint4 kreg = *(const uint4*)(kb + (long)(ms * 1024 + 64) * 64);
  __syncthreads();
  bf16x8 qf = *(const bf16x8*)&Qs[(wn * 16 + lr) * 40 + lq * 8];
  float mx4[4] = {-1e30f, -1e30f, -1e30f, -1e30f};
  for (int it = 0; it < 16; ++it) {
    const int p = it & 1;
    *(uint4*)&Ks[p ^ 1][krow * 40 + kcq] = kreg;     // stage it+1
    int itn = it + 2; if (itn >= 16) itn = 0;        // wrapped dummy
    kreg = *(const uint4*)(kb + (long)(ms * 1024 + itn * 64) * 64);
    #pragma unroll
    for (int s = 0; s < 2; ++s) {
      int msub = wc * 2 + s;
      bf16x8 kf = *(const bf16x8*)&Ks[p][(msub * 16 + lr) * 40 + lq * 8];
      f32x4 S = {};
      S = __builtin_amdgcn_mfma_f32_16x16x32_bf16(qf, kf, S, 0, 0, 0);
      #pragma unroll
      for (int r = 0; r < 4; ++r) mx4[r] = fmaxf(mx4[r], S[r]);
    }
    __syncthreads();   // Ks[p^1] visible for next iter
  }
  #pragma unroll
  for (int r = 0; r < 4; ++r) red[w][wn * 16 + lq * 4 + r][lr] = mx4[r];
  __syncthreads();
  if (t < 32) {
    int wbase = t >> 4;
    float M = -1e30f;
    #pragma unroll
    for (int j = 0; j < 2; ++j)
      #pragma unroll
      for (int l2 = 0; l2 < 16; ++l2)
        M = fmaxf(M, red[wbase + 2 * j][t][l2]);
    pmax[((long)ms * 2 + b) * 4096 + n0 + t] = M;
  }
}

// ---------------- PAM attention: m-split x2, un-normalized partials ----------------
// pam_merge folded in -- rmL computed from the 4 pmax slices in the prologue.
// Otherwise v7 (best measured): Qs+Ks LDS staging, Ps double-buffer (1 barrier/tile),
// V from swizzled layout in named regs, setprio on PV.
__global__ __launch_bounds__(512) void pam_attn(const u16* __restrict__ qkT,
    const u16* __restrict__ vb, const float* __restrict__ pmax,
    float* __restrict__ Obase, float* __restrict__ Sbase) {
  __shared__ u16 Qs[32 * 40];
  __shared__ u16 Ks[2][64 * 40];
  __shared__ u16 Ps[2][32 * 72];
  __shared__ float rmL[32];
  __shared__ float srow[32];
  const int t = threadIdx.x;
  const int mh = blockIdx.y;
  const int b = blockIdx.z;
  const int n0 = blockIdx.x * 32;
  const int w = t >> 6, l = t & 63, lq = l >> 4, lr = l & 15;
  const int nf = w & 1;
  const int mf = w >> 1;
  const int cw = w * 32;
  float* O = Obase + (long)mh * 2097152;
  float* S = Sbase + (long)mh * 8192;
  if (t < 128) {
    int row = t >> 2, cq = (t & 3) * 8;
    *(uint4*)&Qs[row * 40 + cq] = *(const uint4*)(qkT + ((long)b * 4096 + n0 + row) * 64 + cq);
  }
  if (t < 32) {
    float m = pmax[(long)b * 4096 + n0 + t];
    #pragma unroll
    for (int ms2 = 1; ms2 < 4; ++ms2)
      m = fmaxf(m, pmax[((long)ms2 * 2 + b) * 4096 + n0 + t]);
    rmL[t] = m * LOG2E; srow[t] = 0.f;
  }
  const int krow = t >> 3, kc4 = (t & 7) * 4;
  const u16* kbase = qkT + ((long)b * 4096 + krow) * 64 + 32 + kc4;
  const u16* vop = vb + (long)b * 1048576 + (cw + lr) * 32 + lq * 8;
  const int mStart = mh * 2048, mEnd = mStart + 2048;

  {
    uint2 k0 = *(const uint2*)(kbase + (long)mStart * 64);
    *(uint2*)&Ks[0][krow * 40 + kc4] = k0;
  }
  uint2 kreg = *(const uint2*)(kbase + (long)(mStart + 64) * 64);
  long vt0 = (long)(mStart >> 5) * 8192;
  uint4 vA00 = *(const uint4*)(vop + vt0);
  uint4 vA01 = *(const uint4*)(vop + vt0 + 512);
  uint4 vA10 = *(const uint4*)(vop + vt0 + 8192);
  uint4 vA11 = *(const uint4*)(vop + vt0 + 8704);
  uint4 vB00, vB01, vB10, vB11;

  __syncthreads();
  bf16x8 qf = *(const bf16x8*)&Qs[(nf * 16 + lr) * 40 + lq * 8];
  const float rml = rmL[nf * 16 + lr];
  float spl = 0.f;
  f32x4 acc[2][2] = {};

#define QK_PHASE(KBUF, PBUF)                                                   \
  {                                                                            \
    bf16x8 kf = *(const bf16x8*)&Ks[KBUF][(mf * 16 + lr) * 40 + lq * 8];       \
    f32x4 Sv = {};                                                             \
    Sv = __builtin_amdgcn_mfma_f32_16x16x32_bf16(kf, qf, Sv, 0, 0, 0);         \
    union { u16 h[4]; uint2 q; } pk;                                           \
    _Pragma("unroll")                                                          \
    for (int r = 0; r < 4; ++r) {                                              \
      float p = exp2f(Sv[r] * LOG2E - rml);                                    \
      spl += p;                                                                \
      pk.h[r] = f2b_trunc(p);                                                  \
    }                                                                          \
    *(uint2*)&Ps[PBUF][(nf * 16 + lr) * 72 + mf * 16 + lq * 4] = pk.q;         \
  }

#define PV_PHASE(PBUF, V00, V01, V10, V11)                                     \
  {                                                                            \
    bf16x8 pf0 = *(const bf16x8*)&Ps[PBUF][lr * 72 + lq * 8];                  \
    bf16x8 pf1 = *(const bf16x8*)&Ps[PBUF][(16 + lr) * 72 + lq * 8];           \
    acc[0][0] = __builtin_amdgcn_mfma_f32_16x16x32_bf16(*(bf16x8*)&V00, pf0, acc[0][0], 0, 0, 0); \
    acc[0][1] = __builtin_amdgcn_mfma_f32_16x16x32_bf16(*(bf16x8*)&V00, pf1, acc[0][1], 0, 0, 0); \
    acc[1][0] = __builtin_amdgcn_mfma_f32_16x16x32_bf16(*(bf16x8*)&V01, pf0, acc[1][0], 0, 0, 0); \
    acc[1][1] = __builtin_amdgcn_mfma_f32_16x16x32_bf16(*(bf16x8*)&V01, pf1, acc[1][1], 0, 0, 0); \
    pf0 = *(const bf16x8*)&Ps[PBUF][lr * 72 + 32 + lq * 8];                    \
    pf1 = *(const bf16x8*)&Ps[PBUF][(16 + lr) * 72 + 32 + lq * 8];             \
    acc[0][0] = __builtin_amdgcn_mfma_f32_16x16x32_bf16(*(bf16x8*)&V10, pf0, acc[0][0], 0, 0, 0); \
    acc[0][1] = __builtin_amdgcn_mfma_f32_16x16x32_bf16(*(bf16x8*)&V10, pf1, acc[0][1], 0, 0, 0); \
    acc[1][0] = __builtin_amdgcn_mfma_f32_16x16x32_bf16(*(bf16x8*)&V11, pf0, acc[1][0], 0, 0, 0); \
    acc[1][1] = __builtin_amdgcn_mfma_f32_16x16x32_bf16(*(bf16x8*)&V11, pf1, acc[1][1], 0, 0, 0); \
  }

  #pragma unroll 1
  for (int m0 = mStart; m0 < mEnd; m0 += 128) {
    int m2 = m0 + 128; if (m2 >= mEnd) m2 = mStart;
    int m3 = m0 + 192; if (m3 >= mEnd) m3 = mStart;
    // ---- half A: tile m0 (K in Ks[0], V in vA, P -> Ps[0]) ----
    QK_PHASE(0, 0)
    *(uint2*)&Ks[1][krow * 40 + kc4] = kreg;
    kreg = *(const uint2*)(kbase + (long)m2 * 64);
    {
      long vt = (long)((m0 + 64) >> 5) * 8192;
      vB00 = *(const uint4*)(vop + vt);
      vB01 = *(const uint4*)(vop + vt + 512);
      vB10 = *(const uint4*)(vop + vt + 8192);
      vB11 = *(const uint4*)(vop + vt + 8704);
    }
    __syncthreads();             // Ps[0] + Ks[1] visible
    __builtin_amdgcn_s_setprio(1);
    PV_PHASE(0, vA00, vA01, vA10, vA11)
    __builtin_amdgcn_s_setprio(0);
    // ---- half B: tile m0+64 (K in Ks[1], V in vB, P -> Ps[1]); no barrier between ----
    QK_PHASE(1, 1)
    *(uint2*)&Ks[0][krow * 40 + kc4] = kreg;
    kreg = *(const uint2*)(kbase + (long)m3 * 64);
    {
      long vt = (long)(m2 >> 5) * 8192;
      vA00 = *(const uint4*)(vop + vt);
      vA01 = *(const uint4*)(vop + vt + 512);
      vA10 = *(const uint4*)(vop + vt + 8192);
      vA11 = *(const uint4*)(vop + vt + 8704);
    }
    __syncthreads();             // Ps[1] + Ks[0] visible
    __builtin_amdgcn_s_setprio(1);
    PV_PHASE(1, vB00, vB01, vB10, vB11)
    __builtin_amdgcn_s_setprio(0);
  }
#undef QK_PHASE
#undef PV_PHASE

  spl += __shfl_xor(spl, 16);
  spl += __shfl_xor(spl, 32);
  if (l < 16) atomicAdd(&srow[nf * 16 + lr], spl);
  __syncthreads();
  if (t < 32) S[(long)b * 4096 + n0 + t] = srow[t];
  float* ob = O + (long)b * 1048576 + n0;
  #pragma unroll
  for (int cf = 0; cf < 2; ++cf) {
    #pragma unroll
    for (int r = 0; r < 4; ++r) {
      int c = cw + cf * 16 + lq * 4 + r;
      ob[(long)c * 4096 + lr]      = acc[cf][0][r];
      ob[(long)c * 4096 + 16 + lr] = acc[cf][1][r];
    }
  }
}

// ---------------- CAM ----------------

__global__ __launch_bounds__(256) void fillz(float* __restrict__ p, int n) {
  int i = blockIdx.x * 256 + threadIdx.x;
  if (i < n) p[i] = 0.f;
}

// e[b,c,d] += sum over this block's K slice (split-K x16)
// double-buffered Bs -> ONE barrier per K-step; A direct-from-global.
__global__ __launch_bounds__(256) void cam_e_mfma(const u16* __restrict__ resb, float* __restrict__ e) {
  __shared__ u16 Bs[2][128 * 40];
  const int t = threadIdx.x;
  const int d0 = blockIdx.x * 128;
  const int c0 = blockIdx.y * 64;
  const int bz = blockIdx.z;
  const int b = bz >> 4, ks = bz & 15;
  const int w = t >> 6, l = t & 63, lq = l >> 4, lr = l & 15;
  const int wo = (w >> 1) * 32, wn = (w & 1) * 64;
  const u16* fb = resb + (long)b * 1048576;
  const u16* a0p = fb + (long)(c0 + wo + lr) * 4096 + lq * 8;
  const u16* a1p = a0p + (long)16 * 4096;
  const int bo = t >> 1, bkq = (t & 1) * 16;
  const u16* bp = fb + (long)(d0 + bo) * 4096 + bkq;
  const int kS = ks * 256, kE = kS + 256;
  f32x4 acc[2][4] = {};
  uint4 b0 = *(const uint4*)(bp + kS);
  uint4 b1 = *(const uint4*)(bp + kS + 8);
  *(uint4*)&Bs[0][bo * 40 + bkq] = b0;
  *(uint4*)&Bs[0][bo * 40 + bkq + 8] = b1;
  b0 = *(const uint4*)(bp + kS + 32);
  b1 = *(const uint4*)(bp + kS + 40);
  uint4 a0 = *(const uint4*)(a0p + kS);
  uint4 a1 = *(const uint4*)(a1p + kS);
  __syncthreads();
  for (int kc = kS; kc < kE; kc += 32) {
    const int p = ((kc - kS) >> 5) & 1;
    *(uint4*)&Bs[p ^ 1][bo * 40 + bkq] = b0;
    *(uint4*)&Bs[p ^ 1][bo * 40 + bkq + 8] = b1;
    int kn = kc + 32; if (kn >= kE) kn = kS;
    int kb = kc + 64; if (kb >= kE) kb = kS;
    uint4 a0n = *(const uint4*)(a0p + kn);
    uint4 a1n = *(const uint4*)(a1p + kn);
    uint4 b0n = *(const uint4*)(bp + kb);
    uint4 b1n = *(const uint4*)(bp + kb + 8);
    #pragma unroll
    for (int j = 0; j < 4; ++j) {
      bf16x8 bfv = *(const bf16x8*)&Bs[p][(wn + j * 16 + lr) * 40 + lq * 8];
      acc[0][j] = __builtin_amdgcn_mfma_f32_16x16x32_bf16(*(const bf16x8*)&a0, bfv, acc[0][j], 0, 0, 0);
      acc[1][j] = __builtin_amdgcn_mfma_f32_16x16x32_bf16(*(const bf16x8*)&a1, bfv, acc[1][j], 0, 0, 0);
    }
    a0 = a0n; a1 = a1n; b0 = b0n; b1 = b1n;
    __syncthreads();
  }
  #pragma unroll
  for (int i = 0; i < 2; ++i)
    #pragma unroll
    for (int r = 0; r < 4; ++r) {
      int ol = wo + i * 16 + lq * 4 + r;
      #pragma unroll
      for (int j = 0; j < 4; ++j)
        atomicAdd(&e[((long)b << 16) + (long)(c0 + ol) * 256 + d0 + wn + j * 16 + lr], acc[i][j][r]);
    }
}

__global__ __launch_bounds__(256) void cam_softmax(const float* __restrict__ e, u16* __restrict__ attn) {
  __shared__ float red[256];
  int c = blockIdx.x, b = blockIdx.y, t = threadIdx.x;
  const float* row = e + ((long)b << 16) + (long)c * 256;
  float v = row[t];
  red[t] = v; __syncthreads();
  for (int s = 128; s > 0; s >>= 1) { if (t < s) red[t] = fminf(red[t], red[t + s]); __syncthreads(); }
  float emin = red[0]; __syncthreads();
  float ex = exp2f(LOG2E * (emin - v));
  red[t] = ex; __syncthreads();
  for (int s = 128; s > 0; s >>= 1) { if (t < s) red[t] += red[t + s]; __syncthreads(); }
  float inv = 1.f / red[0];
  attn[((long)b << 16) + (long)c * 256 + t] = f2b(ex * inv);
}

// ---------------- final combine (fuses PAM partial merge) ----------------

__global__ __launch_bounds__(256) void combine(const float* __restrict__ res, const float* __restrict__ O,
    const float* __restrict__ S, const float* __restrict__ cam, const float* __restrict__ gp,
    void* __restrict__ outp, const float* __restrict__ flagp) {
  int idx = blockIdx.x * 256 + threadIdx.x;
  int b = idx >> 20, n = idx & 4095;
  float g1 = gp[0], g2 = gp[1];
  float sden = S[(long)b * 4096 + n] + S[8192 + (long)b * 4096 + n];
  float pamv = (O[idx] + O[2097152 + idx]) / sden;
  float v = 3.f * res[idx] + g1 * pamv + g2 * cam[idx];
  if (*flagp > 0.5f) ((float*)outp)[idx] = v;
  else               ((u16*)outp)[idx] = f2b(v);
}

// ---------------- launch ----------------

extern "C" void kernel_launch(void* const* d_in, const int* in_sizes, int n_in,
                              void* d_out, int out_size, void* d_ws, size_t ws_size,
                              hipStream_t stream)
{
  (void)out_size; (void)ws_size; (void)n_in;
  float* ws = (float*)d_ws;
  const long CN = 1048576;   // 256*4096

  float* A  = ws;            // r bf16 -> res fp32
  float* Bp = ws + 2 * CN;   // xf fp32 -> s3out/s5out/resb bf16
  float* Cp = ws + 4 * CN;   // CoordAtt smalls -> s1out bf16 -> vb bf16 (V-swizzled)
  float* D  = ws + 6 * CN;   // y12 (incl. early s2 half) -> {attn smalls} -> cam
  const long WFo = 14 * CN;

  u16*   rB   = (u16*)A;
  float* res  = A;
  float* xf   = Bp;
  u16*   BpU  = (u16*)Bp;
  float* yin  = Cp;
  float* ybn  = Cp + 65536;
  u16*   CpU  = (u16*)Cp;
  u16*   y12U = (u16*)D;
  float* D2   = D + 2 * CN;
  u16*   qkTU = (u16*)(D2 + 262144);
  float* pmax = D2 + 524288;
  float* e    = D2 + 565248;
  u16*   attnc= (u16*)(D2 + 696320);
  float* S0   = D2 + 761856;
  float* cam  = D;
  float* O0   = D + 4 * CN;          // ws+10CN..14CN; written by pam_attn (late)
  u16*   catU = (u16*)O0;            // cat shares O0's space -- lifetimes disjoint
                                     // (cat dead after s5; O0 written by pam_attn)

  ConvArgs ca;
  long fOff[30], hOff[30];
  long hcur = 0;
  float* flagp = ws + WFo;
  {
    long cum = 0, fcur = WFo + 4;
    for (int i = 0; i < 30; ++i) {
      ca.src[i] = d_in[i];
      int h = (i == 8 || i == 10 || i == 14 || i == 16 || i == 20 ||
               i == 22 || i == 24 || i == 26) ? 1 : 0;
      ca.mode[i] = h;
      if (i == 0) { ca.dst[i] = 2 * CN; fOff[i] = 2 * CN; }
      else if (h) { ca.dst[i] = hcur; hOff[i] = hcur; hcur += in_sizes[i]; }
      else        { ca.dst[i] = fcur; fOff[i] = fcur; fcur += in_sizes[i]; }
      cum += in_sizes[i];
      ca.end[i] = (int)cum;
    }
  }
  long fTotal = WFo + 4;
  for (int i = 1; i < 30; ++i) if (!ca.mode[i]) fTotal = (fOff[i] + in_sizes[i] > fTotal) ? fOff[i] + in_sizes[i] : fTotal;
  u16* wsH = (u16*)(ws + fTotal);
  u16* wt3a = wsH + hcur;
  u16* wt3b = wsH + hcur + 589824;
  int total = ca.end[29];

  detect_k<<<dim3(1), dim3(128), 0, stream>>>((const u16*)d_in[0], flagp);
  convert_all<<<dim3((total + 255) / 256), dim3(256), 0, stream>>>(ca, ws, wsH, flagp, total);

  float* ca_w1 = ws + fOff[1];
  float* ca_b1 = ws + fOff[2];
  float* ca_bn = ws + fOff[3];
  float* ca_wh = ws + fOff[4];
  float* ca_bh = ws + fOff[5];
  float* ca_ww = ws + fOff[6];
  float* ca_bw = ws + fOff[7];
  u16*   s1_w  = wsH + hOff[8];   float* s1_bn = ws + fOff[9];
  u16*   s2_w  = wsH + hOff[10];  float* s2_bn = ws + fOff[11];
  float* s3_wf = ws + fOff[12];   float* s3_bn = ws + fOff[13];
  u16*   s4_w  = wsH + hOff[14];  float* s4_bn = ws + fOff[15];
  u16*   s5_w  = wsH + hOff[16];  float* s5_bn = ws + fOff[17];
  float* s6_wf = ws + fOff[18];   float* s6_bn = ws + fOff[19];
  u16*   s7_w  = wsH + hOff[20];  float* s7_bn = ws + fOff[21];
  u16*   qk_w  = wsH + hOff[22];  float* qk_b  = ws + fOff[23];
  u16*   pv_w  = wsH + hOff[26];  float* pv_b  = ws + fOff[27];
  float* gammas = ws + fOff[28];

  w3t<<<dim3(2304), dim3(256), 0, stream>>>(s3_wf, wt3a);
  w3t<<<dim3(2304), dim3(256), 0, stream>>>(s6_wf, wt3b);

  // ---- CoordAtt ----
  plane_means<<<dim3(512), dim3(256), 0, stream>>>(xf, yin);
  ca_conv1<<<dim3(2, 8), dim3(128), 0, stream>>>(yin, ca_w1, ca_b1, ca_bn, ybn);
  apply_ca<<<dim3(8192), dim3(256), 0, stream>>>(xf, ybn, ca_wh, ca_bh, ca_ww, ca_bw, rB);

  // ---- SPPCSPC (bf16 activations) ----
  // s1 + s2 fused into ONE dispatch (same input rB); s2 -> y12U+CN (D region),
  // safe now because cat lives at ws+10CN (O0's space), not D.
  mfma_cbs_dual<<<dim3(64, 8, 2), dim3(256), 0, stream>>>(s1_w, s2_w, rB, CN,
                                                          CpU, CN, y12U + CN, 2 * CN, s1_bn, s2_bn);
  conv3_mfma<<<dim3(64, 4, 2), dim3(256), 0, stream>>>(wt3a, CpU, CN, BpU, CN, 256, 256, s3_bn);
  mfma_cbs<1,1><<<dim3(64, 4, 2), dim3(256), 0, stream>>>(s4_w, 0, BpU, CN, catU, 4 * CN, 256, 256, 4096, s4_bn, nullptr, nullptr);

  pool3<<<dim3(256, 2), dim3(256), 0, stream>>>(catU, 4 * CN);

  mfma_cbs<1,1><<<dim3(64, 4, 2), dim3(256), 0, stream>>>(s5_w, 0, catU, 4 * CN, BpU, CN, 256, 1024, 4096, s5_bn, nullptr, nullptr);
  conv3_mfma<<<dim3(64, 4, 2), dim3(256), 0, stream>>>(wt3b, BpU, CN, y12U, 2 * CN, 256, 256, s6_bn);
  // s7: dual-write fp32 res + bf16 resb (fuses cvtb)
  mfma_cbs<1,4><<<dim3(64, 4, 2), dim3(256), 0, stream>>>(s7_w, 0, y12U, 2 * CN, res, CN, 256, 512, 4096, s7_bn, nullptr, BpU);

  // ---- PAM ----
  // qk: write qkT [n][64] directly (fuses transpose_hh)
  mfma_cbs<0,3><<<dim3(64, 1, 2), dim3(256), 0, stream>>>(qk_w, 0, BpU, CN, qkTU, 262144, 64, 256, 4096, nullptr, qk_b, nullptr);
  mfma_cbs<0,2><<<dim3(64, 4, 2), dim3(256), 0, stream>>>(pv_w, 0, BpU, CN, CpU, CN, 256, 256, 4096, nullptr, pv_b, nullptr);

  pam_qk_max<<<dim3(128, 4, 2), dim3(256), 0, stream>>>(qkTU, pmax);
  pam_attn<<<dim3(128, 2, 2), dim3(512), 0, stream>>>(qkTU, CpU, pmax, O0, S0);

  // ---- CAM ----
  fillz<<<dim3(512), dim3(256), 0, stream>>>(e, 131072);
  cam_e_mfma<<<dim3(2, 4, 32), dim3(256), 0, stream>>>(BpU, e);
  cam_softmax<<<dim3(256, 2), dim3(256), 0, stream>>>(e, attnc);
  mfma_cbs<0,0><<<dim3(64, 4, 2), dim3(256), 0, stream>>>(attnc, 65536, BpU, CN, cam, CN, 256, 256, 4096, nullptr, nullptr, nullptr);

  // ---- combine ----
  combine<<<dim3(8192), dim3(256), 0, stream>>>(res, O0, S0, cam, gammas, d_out, flagp);
}

// Round 13
// 404.373 us; speedup vs baseline: 1.0528x; 1.0121x over previous
//
#include <hip/hip_runtime.h>

typedef unsigned short u16;
typedef __attribute__((ext_vector_type(8))) short bf16x8;
typedef __attribute__((ext_vector_type(4))) float f32x4;
#define EPSV 1e-5f
#define LOG2E 1.4426950408889634f

__device__ __forceinline__ float b2f(u16 u) {
  union { float f; unsigned int i; } v; v.i = ((unsigned int)u) << 16; return v.f;
}
__device__ __forceinline__ u16 f2b(float f) {
  union { float f; unsigned int i; } v; v.f = f;
  unsigned int r = v.i + 0x7FFFu + ((v.i >> 16) & 1u);
  return (u16)(r >> 16);
}
__device__ __forceinline__ u16 f2b_trunc(float f) {
  union { float f; unsigned int i; } v; v.f = f;
  return (u16)(v.i >> 16);
}
__device__ __forceinline__ float silu_(float z) { return z / (1.f + exp2f(-LOG2E * z)); }

// ---------------- dtype detect ----------------
__global__ __launch_bounds__(128) void detect_k(const u16* __restrict__ xp, float* __restrict__ flag) {
  __shared__ int cnt[2];
  int t = threadIdx.x;
  if (t < 2) cnt[t] = 0;
  __syncthreads();
  u16 u = xp[t * 2];
  int e = (u >> 7) & 0xff;
  if (e != 0 && (e < 90 || e > 160)) atomicAdd(&cnt[0], 1);
  if (u == 0) atomicAdd(&cnt[1], 1);
  __syncthreads();
  if (t == 0) *flag = (cnt[0] > 16 || cnt[1] > 64) ? 1.f : 0.f;
}

// ---------------- input conversion ----------------

struct ConvArgs {
  const void* src[30];
  long dst[30];
  int end[30];
  int mode[30];
};

__global__ __launch_bounds__(256) void convert_all(ConvArgs a, float* __restrict__ wsF,
                                                   u16* __restrict__ wsH,
                                                   const float* __restrict__ flagp, int total) {
  const int flag = (*flagp > 0.5f);
  int gid = blockIdx.x * 256 + threadIdx.x;
  if (gid >= total) return;
  #pragma unroll 1
  for (int s = 0; s < 30; ++s) {
    if (gid < a.end[s]) {
      int idx = gid - (s ? a.end[s - 1] : 0);
      if (a.mode[s] == 0) {
        float v = flag ? ((const float*)a.src[s])[idx] : b2f(((const u16*)a.src[s])[idx]);
        wsF[a.dst[s] + idx] = v;
      } else {
        u16 h = flag ? f2b(((const float*)a.src[s])[idx]) : ((const u16*)a.src[s])[idx];
        wsH[a.dst[s] + idx] = h;
      }
      return;
    }
  }
}

// conv3 weight transform: fp32 W[o][I][3][3] -> bf16 Wt[I/32][tap][256o][32ch]
__global__ __launch_bounds__(256) void w3t(const float* __restrict__ Wsrc, u16* __restrict__ Wdst) {
  int idx = blockIdx.x * 256 + threadIdx.x;
  int ch = idx & 31;
  int o  = (idx >> 5) & 255;
  int tap = (idx >> 13) % 9;
  int c8 = (idx >> 13) / 9;
  int i = c8 * 32 + ch;
  Wdst[idx] = f2b(Wsrc[((long)o * 256 + i) * 9 + tap]);
}

// ---------------- CoordAtt ----------------

__global__ __launch_bounds__(256) void plane_means(const float* __restrict__ x, float* __restrict__ yin) {
  __shared__ float pl[4096];
  int bc = blockIdx.x, t = threadIdx.x;
  const float* xp = x + (long)bc * 4096;
  for (int j = 0; j < 16; ++j) { int id = j * 256 + t; pl[id] = xp[id]; }
  __syncthreads();
  if (t < 64) {
    float s = 0.f;
    for (int w = 0; w < 64; ++w) s += pl[t * 64 + w];
    yin[(long)bc * 128 + t] = s * (1.f / 64.f);
  } else if (t < 128) {
    int w = t - 64; float s = 0.f;
    for (int h = 0; h < 64; ++h) s += pl[h * 64 + w];
    yin[(long)bc * 128 + 64 + w] = s * (1.f / 64.f);
  }
}

// grid (2 b x 8 o)
__global__ __launch_bounds__(128) void ca_conv1(const float* __restrict__ yin, const float* __restrict__ w1,
                                                const float* __restrict__ b1, const float* __restrict__ bnp,
                                                float* __restrict__ ybn) {
  int b = blockIdx.x, o = blockIdx.y, p = threadIdx.x;
  float acc = 0.f;
  for (int c = 0; c < 256; ++c)
    acc += w1[o * 256 + c] * yin[((long)b * 256 + c) * 128 + p];
  float z = acc + b1[o];
  float g = bnp[o], bt = bnp[8 + o], mn = bnp[16 + o], vr = bnp[24 + o];
  float s = g * rsqrtf(vr + EPSV);
  z = z * s + (bt - mn * s);
  float hs = fminf(fmaxf(z + 3.f, 0.f), 6.f) * (1.f / 6.f);
  ybn[((long)b * 8 + o) * 128 + p] = z * hs;
}

// ca_gate fused: recompute the two sigmoids per element (ybn is 2KB, L1-hot)
__global__ __launch_bounds__(256) void apply_ca(const float* __restrict__ x, const float* __restrict__ ybn,
    const float* __restrict__ wh, const float* __restrict__ bh,
    const float* __restrict__ ww, const float* __restrict__ bw,
    u16* __restrict__ r) {
  int idx = blockIdx.x * 256 + threadIdx.x;
  int n = idx & 4095, bc = idx >> 12;
  int b = bc >> 8, c = bc & 255;
  int h = n >> 6, w = n & 63;
  const float* yb = ybn + (long)b * 1024;   // [8][128]
  float d1 = bh[c], d2 = bw[c];
  #pragma unroll
  for (int o = 0; o < 8; ++o) {
    d1 += wh[c * 8 + o] * yb[o * 128 + h];
    d2 += ww[c * 8 + o] * yb[o * 128 + 64 + w];
  }
  float ah = 1.f / (1.f + exp2f(-LOG2E * d1));
  float aw = 1.f / (1.f + exp2f(-LOG2E * d2));
  r[idx] = f2b(x[idx] * ah * aw);
}

// ---------------- MFMA 1x1 conv, 64o x 64n tile: bf16 in (BK=32, best measured) -------
// double-buffered Bs -> ONE barrier per K-step; A direct-from-global named regs.
// OUTH: 0 = fp32 linear, 1 = bf16 linear [ch][n], 2 = bf16 V-swizzled [n/32][ch][n%32],
//       3 = bf16 TRANSPOSED [n][64] (fuses transpose_hh), 4 = fp32 + bf16 dual (fuses cvtb)

template<int ACT, int OUTH>
__global__ __launch_bounds__(256) void mfma_cbs(
    const u16* __restrict__ Wbf, long aBS,
    const u16* __restrict__ In, long bBS,
    void* __restrict__ Out, long oBS,
    int O, int K, int N,
    const float* __restrict__ bnp, const float* __restrict__ bias,
    void* __restrict__ Out2)
{
  __shared__ u16 Bs[2][64 * 40];
  __shared__ float albe[64][2];
  const int t = threadIdx.x;
  const int n0 = blockIdx.x * 64;
  const int o0 = blockIdx.y * 64;
  const int b  = blockIdx.z;
  const int w = t >> 6, l = t & 63, lq = l >> 4, lr = l & 15;
  const int wo = (w >> 1) * 32, wn = (w & 1) * 32;
  if (t < 64) {
    int o = o0 + t;
    float al = 1.f, be = 0.f;
    if (bnp) {
      float g = bnp[o], bt = bnp[O + o], mn = bnp[2 * O + o], vr = bnp[3 * O + o];
      al = g * rsqrtf(vr + EPSV); be = bt - mn * al;
    }
    if (bias) be += bias[o];
    albe[t][0] = al; albe[t][1] = be;
  }
  const u16* Ab = Wbf + (long)b * aBS;
  const u16* inb = In + (long)b * bBS + n0;
  const u16* a0p = Ab + (long)(o0 + wo + lr) * K + lq * 8;
  const u16* a1p = a0p + (long)16 * K;
  const int bk = t >> 3, bn8 = (t & 7) * 8;
  f32x4 acc[2][2] = {};
  // prologue: stage Bs[0] (kc=0); prefetch B(kc=32) + A(kc=0)
  uint4 b0 = *(const uint4*)(inb + (long)bk * N + bn8);
  {
    union { uint4 q; u16 h[8]; } tb; tb.q = b0;
    #pragma unroll
    for (int j = 0; j < 8; ++j) Bs[0][(bn8 + j) * 40 + bk] = tb.h[j];
  }
  b0 = *(const uint4*)(inb + (long)(32 + bk) * N + bn8);   // K >= 256 always
  uint4 a0 = *(const uint4*)(a0p);
  uint4 a1 = *(const uint4*)(a1p);
  __syncthreads();
  for (int kc = 0; kc < K; kc += 32) {
    const int p = (kc >> 5) & 1;
    {
      union { uint4 q; u16 h[8]; } tb; tb.q = b0;
      #pragma unroll
      for (int j = 0; j < 8; ++j) Bs[p ^ 1][(bn8 + j) * 40 + bk] = tb.h[j];
    }
    int kn = kc + 32; if (kn >= K) kn = 0;
    int kb = kc + 64; if (kb >= K) kb = 0;
    uint4 a0n = *(const uint4*)(a0p + kn);
    uint4 a1n = *(const uint4*)(a1p + kn);
    uint4 b0n = *(const uint4*)(inb + (long)(kb + bk) * N + bn8);
    bf16x8 bfv0 = *(const bf16x8*)&Bs[p][(wn + lr) * 40 + lq * 8];
    bf16x8 bfv1 = *(const bf16x8*)&Bs[p][(wn + 16 + lr) * 40 + lq * 8];
    acc[0][0] = __builtin_amdgcn_mfma_f32_16x16x32_bf16(*(const bf16x8*)&a0, bfv0, acc[0][0], 0, 0, 0);
    acc[0][1] = __builtin_amdgcn_mfma_f32_16x16x32_bf16(*(const bf16x8*)&a0, bfv1, acc[0][1], 0, 0, 0);
    acc[1][0] = __builtin_amdgcn_mfma_f32_16x16x32_bf16(*(const bf16x8*)&a1, bfv0, acc[1][0], 0, 0, 0);
    acc[1][1] = __builtin_amdgcn_mfma_f32_16x16x32_bf16(*(const bf16x8*)&a1, bfv1, acc[1][1], 0, 0, 0);
    a0 = a0n; a1 = a1n; b0 = b0n;
    __syncthreads();
  }
  float* ob = (float*)Out + (long)b * oBS;
  u16* obh = (u16*)Out + (long)b * oBS;
  u16* obh2 = Out2 ? (u16*)Out2 + (long)b * oBS : nullptr;
  if (OUTH == 3) {
    #pragma unroll
    for (int i = 0; i < 2; ++i) {
      #pragma unroll
      for (int j = 0; j < 2; ++j) {
        int n = n0 + wn + j * 16 + lr;
        union { u16 h[4]; uint2 q; } pk;
        #pragma unroll
        for (int r = 0; r < 4; ++r) {
          int ol = wo + i * 16 + lq * 4 + r;
          float vv = acc[i][j][r] * albe[ol][0] + albe[ol][1];
          if (ACT) vv = silu_(vv);
          pk.h[r] = f2b(vv);
        }
        *(uint2*)&obh[(long)n * 64 + o0 + wo + i * 16 + lq * 4] = pk.q;
      }
    }
  } else {
    #pragma unroll
    for (int i = 0; i < 2; ++i) {
      #pragma unroll
      for (int r = 0; r < 4; ++r) {
        int ol = wo + i * 16 + lq * 4 + r;
        float al = albe[ol][0], be = albe[ol][1];
        #pragma unroll
        for (int j = 0; j < 2; ++j) {
          float vv = acc[i][j][r] * al + be;
          if (ACT) vv = silu_(vv);
          if (OUTH == 2) {
            int col = n0 + wn + j * 16 + lr;
            obh[((long)(col >> 5) * 256 + (o0 + ol)) * 32 + (col & 31)] = f2b(vv);
          } else if (OUTH == 1) {
            obh[(long)(o0 + ol) * N + n0 + wn + j * 16 + lr] = f2b(vv);
          } else {  // 0 or 4: fp32 linear
            ob[(long)(o0 + ol) * N + n0 + wn + j * 16 + lr] = vv;
            if (OUTH == 4)
              obh2[(long)(o0 + ol) * N + n0 + wn + j * 16 + lr] = f2b(vv);
          }
        }
      }
    }
  }
}

// ---------------- dual GEMM: s1 and s2 in ONE dispatch (same input rB, ACT=1, OUTH=1) --
// grid.y in [0,8): sel = y>>2 picks {W,bn,Out}; o0 = (y&3)*64. K=256, N=4096.
__global__ __launch_bounds__(256) void mfma_cbs_dual(
    const u16* __restrict__ Wa, const u16* __restrict__ Wb,
    const u16* __restrict__ In, long bBS,
    u16* __restrict__ OutA, long oBSa,
    u16* __restrict__ OutB, long oBSb,
    const float* __restrict__ bnA, const float* __restrict__ bnB)
{
  __shared__ u16 Bs[2][64 * 40];
  __shared__ float albe[64][2];
  const int t = threadIdx.x;
  const int n0 = blockIdx.x * 64;
  const int sel = blockIdx.y >> 2;
  const int o0 = (blockIdx.y & 3) * 64;
  const int b  = blockIdx.z;
  const u16* Wbf = sel ? Wb : Wa;
  const float* bnp = sel ? bnB : bnA;
  u16* Out = sel ? OutB : OutA;
  const long oBS = sel ? oBSb : oBSa;
  const int K = 256, N = 4096, O = 256;
  const int w = t >> 6, l = t & 63, lq = l >> 4, lr = l & 15;
  const int wo = (w >> 1) * 32, wn = (w & 1) * 32;
  if (t < 64) {
    int o = o0 + t;
    float g = bnp[o], bt = bnp[O + o], mn = bnp[2 * O + o], vr = bnp[3 * O + o];
    float al = g * rsqrtf(vr + EPSV);
    albe[t][0] = al; albe[t][1] = bt - mn * al;
  }
  const u16* inb = In + (long)b * bBS + n0;
  const u16* a0p = Wbf + (long)(o0 + wo + lr) * K + lq * 8;
  const u16* a1p = a0p + (long)16 * K;
  const int bk = t >> 3, bn8 = (t & 7) * 8;
  f32x4 acc[2][2] = {};
  uint4 b0 = *(const uint4*)(inb + (long)bk * N + bn8);
  {
    union { uint4 q; u16 h[8]; } tb; tb.q = b0;
    #pragma unroll
    for (int j = 0; j < 8; ++j) Bs[0][(bn8 + j) * 40 + bk] = tb.h[j];
  }
  b0 = *(const uint4*)(inb + (long)(32 + bk) * N + bn8);
  uint4 a0 = *(const uint4*)(a0p);
  uint4 a1 = *(const uint4*)(a1p);
  __syncthreads();
  for (int kc = 0; kc < K; kc += 32) {
    const int p = (kc >> 5) & 1;
    {
      union { uint4 q; u16 h[8]; } tb; tb.q = b0;
      #pragma unroll
      for (int j = 0; j < 8; ++j) Bs[p ^ 1][(bn8 + j) * 40 + bk] = tb.h[j];
    }
    int kn = kc + 32; if (kn >= K) kn = 0;
    int kb = kc + 64; if (kb >= K) kb = 0;
    uint4 a0n = *(const uint4*)(a0p + kn);
    uint4 a1n = *(const uint4*)(a1p + kn);
    uint4 b0n = *(const uint4*)(inb + (long)(kb + bk) * N + bn8);
    bf16x8 bfv0 = *(const bf16x8*)&Bs[p][(wn + lr) * 40 + lq * 8];
    bf16x8 bfv1 = *(const bf16x8*)&Bs[p][(wn + 16 + lr) * 40 + lq * 8];
    acc[0][0] = __builtin_amdgcn_mfma_f32_16x16x32_bf16(*(const bf16x8*)&a0, bfv0, acc[0][0], 0, 0, 0);
    acc[0][1] = __builtin_amdgcn_mfma_f32_16x16x32_bf16(*(const bf16x8*)&a0, bfv1, acc[0][1], 0, 0, 0);
    acc[1][0] = __builtin_amdgcn_mfma_f32_16x16x32_bf16(*(const bf16x8*)&a1, bfv0, acc[1][0], 0, 0, 0);
    acc[1][1] = __builtin_amdgcn_mfma_f32_16x16x32_bf16(*(const bf16x8*)&a1, bfv1, acc[1][1], 0, 0, 0);
    a0 = a0n; a1 = a1n; b0 = b0n;
    __syncthreads();
  }
  u16* obh = Out + (long)b * oBS;
  #pragma unroll
  for (int i = 0; i < 2; ++i) {
    #pragma unroll
    for (int r = 0; r < 4; ++r) {
      int ol = wo + i * 16 + lq * 4 + r;
      float al = albe[ol][0], be = albe[ol][1];
      #pragma unroll
      for (int j = 0; j < 2; ++j) {
        float vv = silu_(acc[i][j][r] * al + be);
        obh[(long)(o0 + ol) * N + n0 + wn + j * 16 + lr] = f2b(vv);
      }
    }
  }
}

// ---------------- dual GEMM: qk and pv in ONE dispatch (same input resb, ACT=0) --------
// grid.y in [0,5): y==0 -> qk (O=64, OUTH=3 transposed [n][64], bias qk_b);
//                  y in [1,5) -> pv (O=256, o0=(y-1)*64, OUTH=2 V-swizzled, bias pv_b).
__global__ __launch_bounds__(256) void mfma_cbs_qkpv(
    const u16* __restrict__ Wq, const u16* __restrict__ Wv,
    const u16* __restrict__ In, long bBS,
    u16* __restrict__ OutQ, long oBSq,
    u16* __restrict__ OutV, long oBSv,
    const float* __restrict__ bq, const float* __restrict__ bv)
{
  __shared__ u16 Bs[2][64 * 40];
  __shared__ float albe[64][2];
  const int t = threadIdx.x;
  const int n0 = blockIdx.x * 64;
  const int isQ = (blockIdx.y == 0);
  const int o0 = isQ ? 0 : (blockIdx.y - 1) * 64;
  const int b  = blockIdx.z;
  const u16* Wbf = isQ ? Wq : Wv;
  const float* bias = isQ ? bq : bv;
  const int K = 256, N = 4096;
  const int w = t >> 6, l = t & 63, lq = l >> 4, lr = l & 15;
  const int wo = (w >> 1) * 32, wn = (w & 1) * 32;
  if (t < 64) {
    albe[t][0] = 1.f;
    albe[t][1] = bias[o0 + t];
  }
  const u16* inb = In + (long)b * bBS + n0;
  const u16* a0p = Wbf + (long)(o0 + wo + lr) * K + lq * 8;
  const u16* a1p = a0p + (long)16 * K;
  const int bk = t >> 3, bn8 = (t & 7) * 8;
  f32x4 acc[2][2] = {};
  uint4 b0 = *(const uint4*)(inb + (long)bk * N + bn8);
  {
    union { uint4 q; u16 h[8]; } tb; tb.q = b0;
    #pragma unroll
    for (int j = 0; j < 8; ++j) Bs[0][(bn8 + j) * 40 + bk] = tb.h[j];
  }
  b0 = *(const uint4*)(inb + (long)(32 + bk) * N + bn8);
  uint4 a0 = *(const uint4*)(a0p);
  uint4 a1 = *(const uint4*)(a1p);
  __syncthreads();
  for (int kc = 0; kc < K; kc += 32) {
    const int p = (kc >> 5) & 1;
    {
      union { uint4 q; u16 h[8]; } tb; tb.q = b0;
      #pragma unroll
      for (int j = 0; j < 8; ++j) Bs[p ^ 1][(bn8 + j) * 40 + bk] = tb.h[j];
    }
    int kn = kc + 32; if (kn >= K) kn = 0;
    int kb = kc + 64; if (kb >= K) kb = 0;
    uint4 a0n = *(const uint4*)(a0p + kn);
    uint4 a1n = *(const uint4*)(a1p + kn);
    uint4 b0n = *(const uint4*)(inb + (long)(kb + bk) * N + bn8);
    bf16x8 bfv0 = *(const bf16x8*)&Bs[p][(wn + lr) * 40 + lq * 8];
    bf16x8 bfv1 = *(const bf16x8*)&Bs[p][(wn + 16 + lr) * 40 + lq * 8];
    acc[0][0] = __builtin_amdgcn_mfma_f32_16x16x32_bf16(*(const bf16x8*)&a0, bfv0, acc[0][0], 0, 0, 0);
    acc[0][1] = __builtin_amdgcn_mfma_f32_16x16x32_bf16(*(const bf16x8*)&a0, bfv1, acc[0][1], 0, 0, 0);
    acc[1][0] = __builtin_amdgcn_mfma_f32_16x16x32_bf16(*(const bf16x8*)&a1, bfv0, acc[1][0], 0, 0, 0);
    acc[1][1] = __builtin_amdgcn_mfma_f32_16x16x32_bf16(*(const bf16x8*)&a1, bfv1, acc[1][1], 0, 0, 0);
    a0 = a0n; a1 = a1n; b0 = b0n;
    __syncthreads();
  }
  if (isQ) {
    u16* obh = OutQ + (long)b * oBSq;
    #pragma unroll
    for (int i = 0; i < 2; ++i) {
      #pragma unroll
      for (int j = 0; j < 2; ++j) {
        int n = n0 + wn + j * 16 + lr;
        union { u16 h[4]; uint2 q; } pk;
        #pragma unroll
        for (int r = 0; r < 4; ++r) {
          int ol = wo + i * 16 + lq * 4 + r;
          pk.h[r] = f2b(acc[i][j][r] + albe[ol][1]);
        }
        *(uint2*)&obh[(long)n * 64 + wo + i * 16 + lq * 4] = pk.q;
      }
    }
  } else {
    u16* obh = OutV + (long)b * oBSv;
    #pragma unroll
    for (int i = 0; i < 2; ++i) {
      #pragma unroll
      for (int r = 0; r < 4; ++r) {
        int ol = wo + i * 16 + lq * 4 + r;
        float be = albe[ol][1];
        #pragma unroll
        for (int j = 0; j < 2; ++j) {
          int col = n0 + wn + j * 16 + lr;
          obh[((long)(col >> 5) * 256 + (o0 + ol)) * 32 + (col & 31)] = f2b(acc[i][j][r] + be);
        }
      }
    }
  }
}

// ---------------- MFMA 3x3 conv (implicit GEMM), bf16 in/out ----------------
// one output ROW per block (512 blocks = 2/CU); 3-row double-buffered stage ->
// ONE barrier per c8 step; weights direct-from-global; wave = 64o x 16px.
__global__ __launch_bounds__(256) void conv3_mfma(
    const u16* __restrict__ Wt,
    const u16* __restrict__ In, long iBS,
    u16* __restrict__ Out, long oBS, int O, int I,
    const float* __restrict__ bnp)
{
  __shared__ u16 Bs[2][3 * 66 * 34];
  __shared__ float albe[64][2];
  const int t = threadIdx.x;
  const int h0 = blockIdx.x;
  const int o0 = blockIdx.y * 64;
  const int b  = blockIdx.z;
  const int w = t >> 6, l = t & 63, lq = l >> 4, lr = l & 15;
  const int wn = w * 16;
  if (t < 64) {
    int o = o0 + t;
    float g = bnp[o], bt = bnp[O + o], mn = bnp[2 * O + o], vr = bnp[3 * O + o];
    float al = g * rsqrtf(vr + EPSV);
    albe[t][0] = al; albe[t][1] = bt - mn * al;
  }
  if (t < 192) {
    int r = t >> 6, cs = (t >> 5) & 1, ch = t & 31;
    Bs[0][(r * 66 + (cs ? 65 : 0)) * 34 + ch] = 0;
    Bs[1][(r * 66 + (cs ? 65 : 0)) * 34 + ch] = 0;
  }
  const u16* inb = In + (long)b * iBS;
  const int bch = t >> 3, bcg = (t & 7) * 8;
  const u16* wlane = Wt + (long)(o0 + lr) * 32 + lq * 8;
  const int nC8 = I >> 5;
  f32x4 acc[4] = {};

  uint4 tb0, tb1, tb2;
  {
    const u16* cb = inb + (long)bch * 4096 + bcg;
    tb0 = (h0 - 1 >= 0) ? *(const uint4*)(cb + (h0 - 1) * 64) : make_uint4(0,0,0,0);
    tb1 = *(const uint4*)(cb + h0 * 64);
    tb2 = (h0 + 1 < 64) ? *(const uint4*)(cb + (h0 + 1) * 64) : make_uint4(0,0,0,0);
  }
  {
    union { uint4 q; u16 h[8]; } u0, u1, u2;
    u0.q = tb0; u1.q = tb1; u2.q = tb2;
    #pragma unroll
    for (int j2 = 0; j2 < 8; ++j2) {
      Bs[0][(0 * 66 + bcg + 1 + j2) * 34 + bch] = u0.h[j2];
      Bs[0][(1 * 66 + bcg + 1 + j2) * 34 + bch] = u1.h[j2];
      Bs[0][(2 * 66 + bcg + 1 + j2) * 34 + bch] = u2.h[j2];
    }
  }
  if (nC8 > 1) {
    const u16* cb = inb + (long)(32 + bch) * 4096 + bcg;
    tb0 = (h0 - 1 >= 0) ? *(const uint4*)(cb + (h0 - 1) * 64) : make_uint4(0,0,0,0);
    tb1 = *(const uint4*)(cb + h0 * 64);
    tb2 = (h0 + 1 < 64) ? *(const uint4*)(cb + (h0 + 1) * 64) : make_uint4(0,0,0,0);
  }
  __syncthreads();

  for (int c8 = 0; c8 < nC8; ++c8) {
    const int p = c8 & 1;
    {
      union { uint4 q; u16 h[8]; } u0, u1, u2;
      u0.q = tb0; u1.q = tb1; u2.q = tb2;
      #pragma unroll
      for (int j2 = 0; j2 < 8; ++j2) {
        Bs[p ^ 1][(0 * 66 + bcg + 1 + j2) * 34 + bch] = u0.h[j2];
        Bs[p ^ 1][(1 * 66 + bcg + 1 + j2) * 34 + bch] = u1.h[j2];
        Bs[p ^ 1][(2 * 66 + bcg + 1 + j2) * 34 + bch] = u2.h[j2];
      }
    }
    int c8n = c8 + 2; if (c8n >= nC8) c8n = 0;
    {
      const u16* cb = inb + (long)(c8n * 32 + bch) * 4096 + bcg;
      uint4 n0_ = (h0 - 1 >= 0) ? *(const uint4*)(cb + (h0 - 1) * 64) : make_uint4(0,0,0,0);
      uint4 n1_ = *(const uint4*)(cb + h0 * 64);
      uint4 n2_ = (h0 + 1 < 64) ? *(const uint4*)(cb + (h0 + 1) * 64) : make_uint4(0,0,0,0);
      const u16* wc8 = wlane + (long)c8 * 9 * 256 * 32;
      #pragma unroll
      for (int dy = 0; dy < 3; ++dy) {
        #pragma unroll
        for (int dx = 0; dx < 3; ++dx) {
          const int tap = dy * 3 + dx;
          const u16* wl = wc8 + (long)tap * 256 * 32;
          uint4 af0 = *(const uint4*)(wl);
          uint4 af1 = *(const uint4*)(wl + 16 * 32);
          uint4 af2 = *(const uint4*)(wl + 32 * 32);
          uint4 af3 = *(const uint4*)(wl + 48 * 32);
          bf16x8 bv = *(const bf16x8*)&Bs[p][(dy * 66 + wn + dx + lr) * 34 + lq * 8];
          acc[0] = __builtin_amdgcn_mfma_f32_16x16x32_bf16(*(const bf16x8*)&af0, bv, acc[0], 0, 0, 0);
          acc[1] = __builtin_amdgcn_mfma_f32_16x16x32_bf16(*(const bf16x8*)&af1, bv, acc[1], 0, 0, 0);
          acc[2] = __builtin_amdgcn_mfma_f32_16x16x32_bf16(*(const bf16x8*)&af2, bv, acc[2], 0, 0, 0);
          acc[3] = __builtin_amdgcn_mfma_f32_16x16x32_bf16(*(const bf16x8*)&af3, bv, acc[3], 0, 0, 0);
        }
      }
      tb0 = n0_; tb1 = n1_; tb2 = n2_;
    }
    __syncthreads();
  }
  u16* ob = Out + (long)b * oBS;
  const int n0 = h0 * 64;
  #pragma unroll
  for (int i = 0; i < 4; ++i) {
    #pragma unroll
    for (int r = 0; r < 4; ++r) {
      int ol = i * 16 + lq * 4 + r;
      float al = albe[ol][0], be = albe[ol][1];
      float vv = silu_(acc[i][r] * al + be);
      ob[(long)(o0 + ol) * 4096 + n0 + wn + lr] = f2b(vv);
    }
  }
}

// ---------------- fused chained maxpools: x1 -> mp5 -> mp9 -> mp13 (bf16, in-LDS) ----------------
__global__ __launch_bounds__(256) void pool3(u16* __restrict__ cat, long bs) {
  __shared__ float A[68][72];
  __shared__ float Bb[68][72];
  const int t = threadIdx.x;
  const int c = blockIdx.x, b = blockIdx.y;
  u16* base = cat + (long)b * bs + (long)c * 4096;
  for (int i = t; i < 68 * 72; i += 256) { (&A[0][0])[i] = -1e30f; (&Bb[0][0])[i] = -1e30f; }
  __syncthreads();
  const int r = t >> 2, c0 = (t & 3) * 16;
  #pragma unroll
  for (int j = 0; j < 16; ++j) A[r + 2][c0 + 2 + j] = b2f(base[r * 64 + c0 + j]);
  const long CNu = 1048576;
  #pragma unroll 1
  for (int s = 1; s <= 3; ++s) {
    __syncthreads();
    #pragma unroll
    for (int j = 0; j < 16; ++j) {
      int cc = c0 + j;
      float m = fmaxf(fmaxf(fmaxf(A[r+2][cc], A[r+2][cc+1]), fmaxf(A[r+2][cc+2], A[r+2][cc+3])), A[r+2][cc+4]);
      Bb[r + 2][cc + 2] = m;
    }
    __syncthreads();
    u16* out = base + (long)s * CNu;
    #pragma unroll
    for (int j = 0; j < 16; ++j) {
      int hc = c0 + 2 + j;
      float m = fmaxf(fmaxf(fmaxf(Bb[r][hc], Bb[r+1][hc]), fmaxf(Bb[r+2][hc], Bb[r+3][hc])), Bb[r+4][hc]);
      out[r * 64 + c0 + j] = f2b_trunc(m);
      A[r + 2][hc] = m;
    }
  }
}

// ---------------- PAM row-max via MFMA (qkT: [b][4096][64]) ----------------
// double-buffered Ks + named-reg prefetch -> ONE barrier per iteration.
__global__ __launch_bounds__(256) void pam_qk_max(const u16* __restrict__ qkT, float* __restrict__ pmax) {
  __shared__ u16 Qs[32 * 40];
  __shared__ u16 Ks[2][64 * 40];
  __shared__ float red[4][32][17];
  const int t = threadIdx.x;
  const int b = blockIdx.z, ms = blockIdx.y, n0 = blockIdx.x * 32;
  const int w = t >> 6, l = t & 63, lq = l >> 4, lr = l & 15;
  const int wn = w & 1, wc = w >> 1;
  if (t < 128) {
    int row = t >> 2, cq = (t & 3) * 8;
    *(uint4*)&Qs[row * 40 + cq] = *(const uint4*)(qkT + ((long)b * 4096 + n0 + row) * 64 + cq);
  }
  const int krow = t >> 2, kcq = (t & 3) * 8;
  const u16* kb = qkT + ((long)b * 4096 + krow) * 64 + 32 + kcq;
  {
    uint4 k0 = *(const uint4*)(kb + (long)(ms * 1024) * 64);
    *(uint4*)&Ks[0][krow * 40 + kcq] = k0;
  }
  uint4 kreg = *(const uint4*)(kb + (long)(ms * 1024 + 64) * 64);
  __syncthreads();
  bf16x8 qf = *(const bf16x8*)&Qs[(wn * 16 + lr) * 40 + lq * 8];
  float mx4[4] = {-1e30f, -1e30f, -1e30f, -1e30f};
  for (int it = 0; it < 16; ++it) {
    const int p = it & 1;
    *(uint4*)&Ks[p ^ 1][krow * 40 + kcq] = kreg;     // stage it+1
    int itn = it + 2; if (itn >= 16) itn = 0;        // wrapped dummy
    kreg = *(const uint4*)(kb + (long)(ms * 1024 + itn * 64) * 64);
    #pragma unroll
    for (int s = 0; s < 2; ++s) {
      int msub = wc * 2 + s;
      bf16x8 kf = *(const bf16x8*)&Ks[p][(msub * 16 + lr) * 40 + lq * 8];
      f32x4 S = {};
      S = __builtin_amdgcn_mfma_f32_16x16x32_bf16(qf, kf, S, 0, 0, 0);
      #pragma unroll
      for (int r = 0; r < 4; ++r) mx4[r] = fmaxf(mx4[r], S[r]);
    }
    __syncthreads();   // Ks[p^1] visible for next iter
  }
  #pragma unroll
  for (int r = 0; r < 4; ++r) red[w][wn * 16 + lq * 4 + r][lr] = mx4[r];
  __syncthreads();
  if (t < 32) {
    int wbase = t >> 4;
    float M = -1e30f;
    #pragma unroll
    for (int j = 0; j < 2; ++j)
      #pragma unroll
      for (int l2 = 0; l2 < 16; ++l2)
        M = fmaxf(M, red[wbase + 2 * j][t][l2]);
    pmax[((long)ms * 2 + b) * 4096 + n0 + t] = M;
  }
}

// ---------------- PAM attention: m-split x2, un-normalized partials ----------------
// pam_merge folded in -- rmL computed from the 4 pmax slices in the prologue.
// v7 structure: Qs+Ks LDS staging, Ps double-buffer (1 barrier/tile),
// V from swizzled layout in named regs, setprio on PV.
__global__ __launch_bounds__(512) void pam_attn(const u16* __restrict__ qkT,
    const u16* __restrict__ vb, const float* __restrict__ pmax,
    float* __restrict__ Obase, float* __restrict__ Sbase) {
  __shared__ u16 Qs[32 * 40];
  __shared__ u16 Ks[2][64 * 40];
  __shared__ u16 Ps[2][32 * 72];
  __shared__ float rmL[32];
  __shared__ float srow[32];
  const int t = threadIdx.x;
  const int mh = blockIdx.y;
  const int b = blockIdx.z;
  const int n0 = blockIdx.x * 32;
  const int w = t >> 6, l = t & 63, lq = l >> 4, lr = l & 15;
  const int nf = w & 1;
  const int mf = w >> 1;
  const int cw = w * 32;
  float* O = Obase + (long)mh * 2097152;
  float* S = Sbase + (long)mh * 8192;
  if (t < 128) {
    int row = t >> 2, cq = (t & 3) * 8;
    *(uint4*)&Qs[row * 40 + cq] = *(const uint4*)(qkT + ((long)b * 4096 + n0 + row) * 64 + cq);
  }
  if (t < 32) {
    float m = pmax[(long)b * 4096 + n0 + t];
    #pragma unroll
    for (int ms2 = 1; ms2 < 4; ++ms2)
      m = fmaxf(m, pmax[((long)ms2 * 2 + b) * 4096 + n0 + t]);
    rmL[t] = m * LOG2E; srow[t] = 0.f;
  }
  const int krow = t >> 3, kc4 = (t & 7) * 4;
  const u16* kbase = qkT + ((long)b * 4096 + krow) * 64 + 32 + kc4;
  const u16* vop = vb + (long)b * 1048576 + (cw + lr) * 32 + lq * 8;
  const int mStart = mh * 2048, mEnd = mStart + 2048;

  {
    uint2 k0 = *(const uint2*)(kbase + (long)mStart * 64);
    *(uint2*)&Ks[0][krow * 40 + kc4] = k0;
  }
  uint2 kreg = *(const uint2*)(kbase + (long)(mStart + 64) * 64);
  long vt0 = (long)(mStart >> 5) * 8192;
  uint4 vA00 = *(const uint4*)(vop + vt0);
  uint4 vA01 = *(const uint4*)(vop + vt0 + 512);
  uint4 vA10 = *(const uint4*)(vop + vt0 + 8192);
  uint4 vA11 = *(const uint4*)(vop + vt0 + 8704);
  uint4 vB00, vB01, vB10, vB11;

  __syncthreads();
  bf16x8 qf = *(const bf16x8*)&Qs[(nf * 16 + lr) * 40 + lq * 8];
  const float rml = rmL[nf * 16 + lr];
  float spl = 0.f;
  f32x4 acc[2][2] = {};

#define QK_PHASE(KBUF, PBUF)                                                   \
  {                                                                            \
    bf16x8 kf = *(const bf16x8*)&Ks[KBUF][(mf * 16 + lr) * 40 + lq * 8];       \
    f32x4 Sv = {};                                                             \
    Sv = __builtin_amdgcn_mfma_f32_16x16x32_bf16(kf, qf, Sv, 0, 0, 0);         \
    union { u16 h[4]; uint2 q; } pk;                                           \
    _Pragma("unroll")                                                          \
    for (int r = 0; r < 4; ++r) {                                              \
      float p = exp2f(Sv[r] * LOG2E - rml);                                    \
      spl += p;                                                                \
      pk.h[r] = f2b_trunc(p);                                                  \
    }                                                                          \
    *(uint2*)&Ps[PBUF][(nf * 16 + lr) * 72 + mf * 16 + lq * 4] = pk.q;         \
  }

#define PV_PHASE(PBUF, V00, V01, V10, V11)                                     \
  {                                                                            \
    bf16x8 pf0 = *(const bf16x8*)&Ps[PBUF][lr * 72 + lq * 8];                  \
    bf16x8 pf1 = *(const bf16x8*)&Ps[PBUF][(16 + lr) * 72 + lq * 8];           \
    acc[0][0] = __builtin_amdgcn_mfma_f32_16x16x32_bf16(*(bf16x8*)&V00, pf0, acc[0][0], 0, 0, 0); \
    acc[0][1] = __builtin_amdgcn_mfma_f32_16x16x32_bf16(*(bf16x8*)&V00, pf1, acc[0][1], 0, 0, 0); \
    acc[1][0] = __builtin_amdgcn_mfma_f32_16x16x32_bf16(*(bf16x8*)&V01, pf0, acc[1][0], 0, 0, 0); \
    acc[1][1] = __builtin_amdgcn_mfma_f32_16x16x32_bf16(*(bf16x8*)&V01, pf1, acc[1][1], 0, 0, 0); \
    pf0 = *(const bf16x8*)&Ps[PBUF][lr * 72 + 32 + lq * 8];                    \
    pf1 = *(const bf16x8*)&Ps[PBUF][(16 + lr) * 72 + 32 + lq * 8];             \
    acc[0][0] = __builtin_amdgcn_mfma_f32_16x16x32_bf16(*(bf16x8*)&V10, pf0, acc[0][0], 0, 0, 0); \
    acc[0][1] = __builtin_amdgcn_mfma_f32_16x16x32_bf16(*(bf16x8*)&V10, pf1, acc[0][1], 0, 0, 0); \
    acc[1][0] = __builtin_amdgcn_mfma_f32_16x16x32_bf16(*(bf16x8*)&V11, pf0, acc[1][0], 0, 0, 0); \
    acc[1][1] = __builtin_amdgcn_mfma_f32_16x16x32_bf16(*(bf16x8*)&V11, pf1, acc[1][1], 0, 0, 0); \
  }

  #pragma unroll 1
  for (int m0 = mStart; m0 < mEnd; m0 += 128) {
    int m2 = m0 + 128; if (m2 >= mEnd) m2 = mStart;
    int m3 = m0 + 192; if (m3 >= mEnd) m3 = mStart;
    // ---- half A: tile m0 (K in Ks[0], V in vA, P -> Ps[0]) ----
    QK_PHASE(0, 0)
    *(uint2*)&Ks[1][krow * 40 + kc4] = kreg;
    kreg = *(const uint2*)(kbase + (long)m2 * 64);
    {
      long vt = (long)((m0 + 64) >> 5) * 8192;
      vB00 = *(const uint4*)(vop + vt);
      vB01 = *(const uint4*)(vop + vt + 512);
      vB10 = *(const uint4*)(vop + vt + 8192);
      vB11 = *(const uint4*)(vop + vt + 8704);
    }
    __syncthreads();             // Ps[0] + Ks[1] visible
    __builtin_amdgcn_s_setprio(1);
    PV_PHASE(0, vA00, vA01, vA10, vA11)
    __builtin_amdgcn_s_setprio(0);
    // ---- half B: tile m0+64 (K in Ks[1], V in vB, P -> Ps[1]); no barrier between ----
    QK_PHASE(1, 1)
    *(uint2*)&Ks[0][krow * 40 + kc4] = kreg;
    kreg = *(const uint2*)(kbase + (long)m3 * 64);
    {
      long vt = (long)(m2 >> 5) * 8192;
      vA00 = *(const uint4*)(vop + vt);
      vA01 = *(const uint4*)(vop + vt + 512);
      vA10 = *(const uint4*)(vop + vt + 8192);
      vA11 = *(const uint4*)(vop + vt + 8704);
    }
    __syncthreads();             // Ps[1] + Ks[0] visible
    __builtin_amdgcn_s_setprio(1);
    PV_PHASE(1, vB00, vB01, vB10, vB11)
    __builtin_amdgcn_s_setprio(0);
  }
#undef QK_PHASE
#undef PV_PHASE

  spl += __shfl_xor(spl, 16);
  spl += __shfl_xor(spl, 32);
  if (l < 16) atomicAdd(&srow[nf * 16 + lr], spl);
  __syncthreads();
  if (t < 32) S[(long)b * 4096 + n0 + t] = srow[t];
  float* ob = O + (long)b * 1048576 + n0;
  #pragma unroll
  for (int cf = 0; cf < 2; ++cf) {
    #pragma unroll
    for (int r = 0; r < 4; ++r) {
      int c = cw + cf * 16 + lq * 4 + r;
      ob[(long)c * 4096 + lr]      = acc[cf][0][r];
      ob[(long)c * 4096 + 16 + lr] = acc[cf][1][r];
    }
  }
}

// ---------------- CAM ----------------

__global__ __launch_bounds__(256) void fillz(float* __restrict__ p, int n) {
  int i = blockIdx.x * 256 + threadIdx.x;
  if (i < n) p[i] = 0.f;
}

// e[b,c,d] += sum over this block's K slice (split-K x16)
// double-buffered Bs -> ONE barrier per K-step; A direct-from-global.
__global__ __launch_bounds__(256) void cam_e_mfma(const u16* __restrict__ resb, float* __restrict__ e) {
  __shared__ u16 Bs[2][128 * 40];
  const int t = threadIdx.x;
  const int d0 = blockIdx.x * 128;
  const int c0 = blockIdx.y * 64;
  const int bz = blockIdx.z;
  const int b = bz >> 4, ks = bz & 15;
  const int w = t >> 6, l = t & 63, lq = l >> 4, lr = l & 15;
  const int wo = (w >> 1) * 32, wn = (w & 1) * 64;
  const u16* fb = resb + (long)b * 1048576;
  const u16* a0p = fb + (long)(c0 + wo + lr) * 4096 + lq * 8;
  const u16* a1p = a0p + (long)16 * 4096;
  const int bo = t >> 1, bkq = (t & 1) * 16;
  const u16* bp = fb + (long)(d0 + bo) * 4096 + bkq;
  const int kS = ks * 256, kE = kS + 256;
  f32x4 acc[2][4] = {};
  uint4 b0 = *(const uint4*)(bp + kS);
  uint4 b1 = *(const uint4*)(bp + kS + 8);
  *(uint4*)&Bs[0][bo * 40 + bkq] = b0;
  *(uint4*)&Bs[0][bo * 40 + bkq + 8] = b1;
  b0 = *(const uint4*)(bp + kS + 32);
  b1 = *(const uint4*)(bp + kS + 40);
  uint4 a0 = *(const uint4*)(a0p + kS);
  uint4 a1 = *(const uint4*)(a1p + kS);
  __syncthreads();
  for (int kc = kS; kc < kE; kc += 32) {
    const int p = ((kc - kS) >> 5) & 1;
    *(uint4*)&Bs[p ^ 1][bo * 40 + bkq] = b0;
    *(uint4*)&Bs[p ^ 1][bo * 40 + bkq + 8] = b1;
    int kn = kc + 32; if (kn >= kE) kn = kS;
    int kb = kc + 64; if (kb >= kE) kb = kS;
    uint4 a0n = *(const uint4*)(a0p + kn);
    uint4 a1n = *(const uint4*)(a1p + kn);
    uint4 b0n = *(const uint4*)(bp + kb);
    uint4 b1n = *(const uint4*)(bp + kb + 8);
    #pragma unroll
    for (int j = 0; j < 4; ++j) {
      bf16x8 bfv = *(const bf16x8*)&Bs[p][(wn + j * 16 + lr) * 40 + lq * 8];
      acc[0][j] = __builtin_amdgcn_mfma_f32_16x16x32_bf16(*(const bf16x8*)&a0, bfv, acc[0][j], 0, 0, 0);
      acc[1][j] = __builtin_amdgcn_mfma_f32_16x16x32_bf16(*(const bf16x8*)&a1, bfv, acc[1][j], 0, 0, 0);
    }
    a0 = a0n; a1 = a1n; b0 = b0n; b1 = b1n;
    __syncthreads();
  }
  #pragma unroll
  for (int i = 0; i < 2; ++i)
    #pragma unroll
    for (int r = 0; r < 4; ++r) {
      int ol = wo + i * 16 + lq * 4 + r;
      #pragma unroll
      for (int j = 0; j < 4; ++j)
        atomicAdd(&e[((long)b << 16) + (long)(c0 + ol) * 256 + d0 + wn + j * 16 + lr], acc[i][j][r]);
    }
}

__global__ __launch_bounds__(256) void cam_softmax(const float* __restrict__ e, u16* __restrict__ attn) {
  __shared__ float red[256];
  int c = blockIdx.x, b = blockIdx.y, t = threadIdx.x;
  const float* row = e + ((long)b << 16) + (long)c * 256;
  float v = row[t];
  red[t] = v; __syncthreads();
  for (int s = 128; s > 0; s >>= 1) { if (t < s) red[t] = fminf(red[t], red[t + s]); __syncthreads(); }
  float emin = red[0]; __syncthreads();
  float ex = exp2f(LOG2E * (emin - v));
  red[t] = ex; __syncthreads();
  for (int s = 128; s > 0; s >>= 1) { if (t < s) red[t] += red[t + s]; __syncthreads(); }
  float inv = 1.f / red[0];
  attn[((long)b << 16) + (long)c * 256 + t] = f2b(ex * inv);
}

// ---------------- final combine (fuses PAM partial merge) ----------------

__global__ __launch_bounds__(256) void combine(const float* __restrict__ res, const float* __restrict__ O,
    const float* __restrict__ S, const float* __restrict__ cam, const float* __restrict__ gp,
    void* __restrict__ outp, const float* __restrict__ flagp) {
  int idx = blockIdx.x * 256 + threadIdx.x;
  int b = idx >> 20, n = idx & 4095;
  float g1 = gp[0], g2 = gp[1];
  float sden = S[(long)b * 4096 + n] + S[8192 + (long)b * 4096 + n];
  float pamv = (O[idx] + O[2097152 + idx]) / sden;
  float v = 3.f * res[idx] + g1 * pamv + g2 * cam[idx];
  if (*flagp > 0.5f) ((float*)outp)[idx] = v;
  else               ((u16*)outp)[idx] = f2b(v);
}

// ---------------- launch ----------------

extern "C" void kernel_launch(void* const* d_in, const int* in_sizes, int n_in,
                              void* d_out, int out_size, void* d_ws, size_t ws_size,
                              hipStream_t stream)
{
  (void)out_size; (void)ws_size; (void)n_in;
  float* ws = (float*)d_ws;
  const long CN = 1048576;   // 256*4096

  float* A  = ws;            // r bf16 -> res fp32
  float* Bp = ws + 2 * CN;   // xf fp32 -> s3out/s5out/resb bf16
  float* Cp = ws + 4 * CN;   // CoordAtt smalls -> s1out bf16 -> vb bf16 (V-swizzled)
  float* D  = ws + 6 * CN;   // y12 (incl. early s2 half) -> {attn smalls} -> cam
  const long WFo = 14 * CN;

  u16*   rB   = (u16*)A;
  float* res  = A;
  float* xf   = Bp;
  u16*   BpU  = (u16*)Bp;
  float* yin  = Cp;
  float* ybn  = Cp + 65536;
  u16*   CpU  = (u16*)Cp;
  u16*   y12U = (u16*)D;
  float* D2   = D + 2 * CN;
  u16*   qkTU = (u16*)(D2 + 262144);
  float* pmax = D2 + 524288;
  float* e    = D2 + 565248;
  u16*   attnc= (u16*)(D2 + 696320);
  float* S0   = D2 + 761856;
  float* cam  = D;
  float* O0   = D + 4 * CN;          // ws+10CN..14CN; written by pam_attn (late)
  u16*   catU = (u16*)O0;            // cat shares O0's space -- lifetimes disjoint

  ConvArgs ca;
  long fOff[30], hOff[30];
  long hcur = 0;
  float* flagp = ws + WFo;
  {
    long cum = 0, fcur = WFo + 4;
    for (int i = 0; i < 30; ++i) {
      ca.src[i] = d_in[i];
      int h = (i == 8 || i == 10 || i == 14 || i == 16 || i == 20 ||
               i == 22 || i == 24 || i == 26) ? 1 : 0;
      ca.mode[i] = h;
      if (i == 0) { ca.dst[i] = 2 * CN; fOff[i] = 2 * CN; }
      else if (h) { ca.dst[i] = hcur; hOff[i] = hcur; hcur += in_sizes[i]; }
      else        { ca.dst[i] = fcur; fOff[i] = fcur; fcur += in_sizes[i]; }
      cum += in_sizes[i];
      ca.end[i] = (int)cum;
    }
  }
  long fTotal = WFo + 4;
  for (int i = 1; i < 30; ++i) if (!ca.mode[i]) fTotal = (fOff[i] + in_sizes[i] > fTotal) ? fOff[i] + in_sizes[i] : fTotal;
  u16* wsH = (u16*)(ws + fTotal);
  u16* wt3a = wsH + hcur;
  u16* wt3b = wsH + hcur + 589824;
  int total = ca.end[29];

  detect_k<<<dim3(1), dim3(128), 0, stream>>>((const u16*)d_in[0], flagp);
  convert_all<<<dim3((total + 255) / 256), dim3(256), 0, stream>>>(ca, ws, wsH, flagp, total);

  float* ca_w1 = ws + fOff[1];
  float* ca_b1 = ws + fOff[2];
  float* ca_bn = ws + fOff[3];
  float* ca_wh = ws + fOff[4];
  float* ca_bh = ws + fOff[5];
  float* ca_ww = ws + fOff[6];
  float* ca_bw = ws + fOff[7];
  u16*   s1_w  = wsH + hOff[8];   float* s1_bn = ws + fOff[9];
  u16*   s2_w  = wsH + hOff[10];  float* s2_bn = ws + fOff[11];
  float* s3_wf = ws + fOff[12];   float* s3_bn = ws + fOff[13];
  u16*   s4_w  = wsH + hOff[14];  float* s4_bn = ws + fOff[15];
  u16*   s5_w  = wsH + hOff[16];  float* s5_bn = ws + fOff[17];
  float* s6_wf = ws + fOff[18];   float* s6_bn = ws + fOff[19];
  u16*   s7_w  = wsH + hOff[20];  float* s7_bn = ws + fOff[21];
  u16*   qk_w  = wsH + hOff[22];  float* qk_b  = ws + fOff[23];
  u16*   pv_w  = wsH + hOff[26];  float* pv_b  = ws + fOff[27];
  float* gammas = ws + fOff[28];

  w3t<<<dim3(2304), dim3(256), 0, stream>>>(s3_wf, wt3a);
  w3t<<<dim3(2304), dim3(256), 0, stream>>>(s6_wf, wt3b);
  // fillz early: e's region is dead until CAM; overlaps CoordAtt/SPPCSPC instead of
  // serializing before cam_e_mfma.
  fillz<<<dim3(512), dim3(256), 0, stream>>>(e, 131072);

  // ---- CoordAtt ----
  plane_means<<<dim3(512), dim3(256), 0, stream>>>(xf, yin);
  ca_conv1<<<dim3(2, 8), dim3(128), 0, stream>>>(yin, ca_w1, ca_b1, ca_bn, ybn);
  apply_ca<<<dim3(8192), dim3(256), 0, stream>>>(xf, ybn, ca_wh, ca_bh, ca_ww, ca_bw, rB);

  // ---- SPPCSPC (bf16 activations) ----
  mfma_cbs_dual<<<dim3(64, 8, 2), dim3(256), 0, stream>>>(s1_w, s2_w, rB, CN,
                                                          CpU, CN, y12U + CN, 2 * CN, s1_bn, s2_bn);
  conv3_mfma<<<dim3(64, 4, 2), dim3(256), 0, stream>>>(wt3a, CpU, CN, BpU, CN, 256, 256, s3_bn);
  mfma_cbs<1,1><<<dim3(64, 4, 2), dim3(256), 0, stream>>>(s4_w, 0, BpU, CN, catU, 4 * CN, 256, 256, 4096, s4_bn, nullptr, nullptr);

  pool3<<<dim3(256, 2), dim3(256), 0, stream>>>(catU, 4 * CN);

  mfma_cbs<1,1><<<dim3(64, 4, 2), dim3(256), 0, stream>>>(s5_w, 0, catU, 4 * CN, BpU, CN, 256, 1024, 4096, s5_bn, nullptr, nullptr);
  conv3_mfma<<<dim3(64, 4, 2), dim3(256), 0, stream>>>(wt3b, BpU, CN, y12U, 2 * CN, 256, 256, s6_bn);
  // s7: dual-write fp32 res + bf16 resb (fuses cvtb)
  mfma_cbs<1,4><<<dim3(64, 4, 2), dim3(256), 0, stream>>>(s7_w, 0, y12U, 2 * CN, res, CN, 256, 512, 4096, s7_bn, nullptr, BpU);

  // ---- PAM ----
  // qk + pv fused into ONE dispatch (same input resb); qk -> qkT transposed,
  // pv -> V-swizzled CpU.
  mfma_cbs_qkpv<<<dim3(64, 5, 2), dim3(256), 0, stream>>>(qk_w, pv_w, BpU, CN,
                                                          qkTU, 262144, CpU, CN, qk_b, pv_b);

  pam_qk_max<<<dim3(128, 4, 2), dim3(256), 0, stream>>>(qkTU, pmax);
  pam_attn<<<dim3(128, 2, 2), dim3(512), 0, stream>>>(qkTU, CpU, pmax, O0, S0);

  // ---- CAM ----
  cam_e_mfma<<<dim3(2, 4, 32), dim3(256), 0, stream>>>(BpU, e);
  cam_softmax<<<dim3(256, 2), dim3(256), 0, stream>>>(e, attnc);
  mfma_cbs<0,0><<<dim3(64, 4, 2), dim3(256), 0, stream>>>(attnc, 65536, BpU, CN, cam, CN, 256, 256, 4096, nullptr, nullptr, nullptr);

  // ---- combine ----
  combine<<<dim3(8192), dim3(256), 0, stream>>>(res, O0, S0, cam, gammas, d_out, flagp);
}